// Round 2
// baseline (307.129 us; speedup 1.0000x reference)
//
#include <hip/hip_runtime.h>
#include <stdint.h>
#include <stddef.h>

typedef __bf16 bf16;
typedef __bf16 bf16x8 __attribute__((ext_vector_type(8)));
typedef float  f32x4  __attribute__((ext_vector_type(4)));

typedef __attribute__((address_space(3))) void       lds_void;
typedef __attribute__((address_space(1))) const void gbl_cvoid;

#define ASYNC_CP16(g, l) \
  __builtin_amdgcn_global_load_lds((gbl_cvoid*)(g), (lds_void*)(l), 16, 0, 0)

// chunk swizzle: spreads b128 fragment reads across banks (verified round 5)
__device__ __forceinline__ int swz(int r) { return (r & 7) ^ ((r & 8) >> 1); }

// ---------------------------------------------------------------------------
// Prep kernel: blocks [0,65536) pack adjacency(+I) into 64-bit masks;
// blocks [65536, ...) do the batched fp32->bf16 cast.
// ---------------------------------------------------------------------------
struct CastArgs {
  const float* src[7];
  bf16*        dst[7];
  int          cum[8];
};

__global__ __launch_bounds__(256) void k_prep(
    const int* __restrict__ adj, unsigned long long* __restrict__ mb,
    CastArgs a, int total8)
{
  const int bid = blockIdx.x;
  if (bid < 65536) {
    const int gw   = (int)(((unsigned)bid * 256 + threadIdx.x) >> 6);
    const int lane = threadIdx.x & 63;
    const int av   = adj[(size_t)gw * 64 + lane];
    unsigned long long m = __ballot(av != 0);
    const int row = gw >> 6, wc = gw & 63;
    if ((row >> 6) == wc) m |= 1ull << (row & 63);
    if (lane == 0) mb[gw] = m;
  } else {
    const int g = (bid - 65536) * 256 + threadIdx.x;
    if (g >= total8) return;
    int t = 0;
    while (a.cum[t + 1] <= g) ++t;
    const int i = g - a.cum[t];
    const float4* s = (const float4*)(a.src[t]) + (size_t)i * 2;
    const float4 x0 = s[0], x1 = s[1];
    bf16x8 y;
    y[0] = (bf16)x0.x; y[1] = (bf16)x0.y; y[2] = (bf16)x0.z; y[3] = (bf16)x0.w;
    y[4] = (bf16)x1.x; y[5] = (bf16)x1.y; y[6] = (bf16)x1.z; y[7] = (bf16)x1.w;
    *(bf16x8*)(a.dst[t] + (size_t)i * 8) = y;
  }
}

// ---------------------------------------------------------------------------
// Async-staged GEMM core, templated on m-tile (MT=128: 2x2 waves, 4x4 frags;
// MT=64: 1x4 waves, 4x2 frags). N-tile fixed 128, BK=64.
// ---------------------------------------------------------------------------
template <int MT>
__device__ __forceinline__ void gemm_core_async(
    const bf16* __restrict__ A, const bf16* __restrict__ B,
    bf16* As, bf16* Bs, f32x4 (&acc)[4][(MT == 128) ? 4 : 2],
    int K, int m0, int n0, int kbeg, int kend)
{
  constexpr int FN = (MT == 128) ? 4 : 2;
  constexpr int IA = MT / 32;             // A staging wave-instrs per wave
  const int tid    = threadIdx.x;
  const int lane   = tid & 63;
  const int wave   = tid >> 6;
  const int lane15 = lane & 15;
  const int quad   = lane >> 4;
  const int wm     = (MT == 128) ? ((wave & 1) << 6) : 0;
  const int wn     = (MT == 128) ? ((wave >> 1) << 6) : (wave << 5);

  int srA[IA], soA[IA], srB[4], soB[4];
#pragma unroll
  for (int i = 0; i < IA; ++i) {
    int c  = ((wave * IA + i) << 6) + lane;
    srA[i] = c >> 3;
    soA[i] = ((c & 7) ^ swz(srA[i])) * 8;
  }
#pragma unroll
  for (int i = 0; i < 4; ++i) {
    int c  = ((wave * 4 + i) << 6) + lane;
    srB[i] = c >> 3;
    soB[i] = ((c & 7) ^ swz(srB[i])) * 8;
  }

  const bf16* Ab = A + (size_t)m0 * K;
  const bf16* Bb = B + (size_t)n0 * K;

  for (int k0 = kbeg; k0 < kend; k0 += 64) {
#pragma unroll
    for (int i = 0; i < IA; ++i)
      ASYNC_CP16(Ab + (size_t)srA[i] * K + k0 + soA[i], &As[(wave * IA + i) * 512]);
#pragma unroll
    for (int i = 0; i < 4; ++i)
      ASYNC_CP16(Bb + (size_t)srB[i] * K + k0 + soB[i], &Bs[(wave * 4 + i) * 512]);
    __syncthreads();

#pragma unroll
    for (int kk = 0; kk < 2; ++kk) {
      bf16x8 af[4], bfr[FN];
#pragma unroll
      for (int f = 0; f < 4; ++f) {
        const int ra = wm + f * 16 + lane15;
        af[f] = *(const bf16x8*)&As[ra * 64 + (((kk * 4 + quad) ^ swz(ra)) * 8)];
      }
#pragma unroll
      for (int f = 0; f < FN; ++f) {
        const int rb = wn + f * 16 + lane15;
        bfr[f] = *(const bf16x8*)&Bs[rb * 64 + (((kk * 4 + quad) ^ swz(rb)) * 8)];
      }
#pragma unroll
      for (int fm = 0; fm < 4; ++fm)
#pragma unroll
        for (int fn = 0; fn < FN; ++fn)
          acc[fm][fn] = __builtin_amdgcn_mfma_f32_16x16x32_bf16(
              af[fm], bfr[fn], acc[fm][fn], 0, 0, 0);
    }
    __syncthreads();
  }
}

// FF1: MT=128 full-K GEMM + bias + relu.
__global__ __launch_bounds__(256, 2) void k_gemm(
    const bf16* __restrict__ A, const bf16* __restrict__ B,
    const float* __restrict__ bias, bf16* __restrict__ C,
    int N, int K, int relu)
{
  __shared__ __align__(16) bf16 As[128 * 64];
  __shared__ __align__(16) bf16 Bs[128 * 64];
  const int m0 = blockIdx.x * 128, n0 = blockIdx.y * 128;
  f32x4 acc[4][4] = {};
  gemm_core_async<128>(A, B, As, Bs, acc, K, m0, n0, 0, K);

  const int lane15 = threadIdx.x & 15;
  const int quad   = (threadIdx.x & 63) >> 4;
  const int wave   = threadIdx.x >> 6;
  const int wm = (wave & 1) << 6, wn = (wave >> 1) << 6;
#pragma unroll
  for (int fm = 0; fm < 4; ++fm)
#pragma unroll
    for (int fn = 0; fn < 4; ++fn) {
      const int col = n0 + wn + fn * 16 + lane15;
      const float bv = bias[col];
#pragma unroll
      for (int r = 0; r < 4; ++r) {
        const int row = m0 + wm + fm * 16 + quad * 4 + r;
        float v = acc[fm][fn][r] + bv;
        if (relu) v = fmaxf(v, 0.0f);
        C[(size_t)row * N + col] = (bf16)v;
      }
    }
}

// QKV: one GEMM over concat weights [1536,512] (rows 0-511 Wq, 512-1023 Wk,
// 1024-1535 Wv). MT=64 -> grid (64,12) = 768 blocks. V-projection blocks
// write vt (transposed) via an LDS transpose in the epilogue.
__global__ __launch_bounds__(256, 4) void k_gemm_qkv(
    const bf16* __restrict__ h, const bf16* __restrict__ Wcat,
    const float* __restrict__ bq, const float* __restrict__ bk,
    const float* __restrict__ bv,
    bf16* __restrict__ q, bf16* __restrict__ k, bf16* __restrict__ vt)
{
  __shared__ __align__(16) bf16 SM[64 * 64 + 128 * 64];   // 24 KB
  bf16* As = SM;
  bf16* Bs = SM + 64 * 64;
  const int m0 = blockIdx.x * 64, n0 = blockIdx.y * 128;
  f32x4 acc[4][2] = {};
  gemm_core_async<64>(h, Wcat, As, Bs, acc, 512, m0, n0, 0, 512);

  const int lane15 = threadIdx.x & 15;
  const int quad   = (threadIdx.x & 63) >> 4;
  const int wave   = threadIdx.x >> 6;
  const int wn     = wave << 5;
  const int proj   = n0 >> 9;                  // 0=q 1=k 2=v
  const int ncol0  = n0 & 511;
  const float* bias = (proj == 0) ? bq : (proj == 1) ? bk : bv;

  if (proj < 2) {
    bf16* C = proj ? k : q;
#pragma unroll
    for (int fm = 0; fm < 4; ++fm)
#pragma unroll
      for (int fn = 0; fn < 2; ++fn) {
        const int col = ncol0 + wn + fn * 16 + lane15;
        const float bvv = bias[col];
#pragma unroll
        for (int r = 0; r < 4; ++r) {
          const int row = m0 + fm * 16 + quad * 4 + r;
          C[(size_t)row * 512 + col] = (bf16)(acc[fm][fn][r] + bvv);
        }
      }
  } else {
    // transpose 64(tokens) x 128(vdims) through LDS -> vt[vdim][token]
    __syncthreads();   // K-loop LDS dead
#pragma unroll
    for (int fm = 0; fm < 4; ++fm)
#pragma unroll
      for (int fn = 0; fn < 2; ++fn) {
        const int colL = wn + fn * 16 + lane15;
        const float bvv = bias[ncol0 + colL];
#pragma unroll
        for (int r = 0; r < 4; ++r) {
          const int rowL = fm * 16 + quad * 4 + r;
          SM[colL * 72 + rowL] = (bf16)(acc[fm][fn][r] + bvv);
        }
      }
    __syncthreads();
#pragma unroll
    for (int i = 0; i < 4; ++i) {
      const int c = i * 256 + threadIdx.x;     // 1024 chunks
      const int colL = c >> 3, rw = (c & 7) * 8;
      *(bf16x8*)&vt[(size_t)(ncol0 + colL) * 4096 + m0 + rw] =
          *(const bf16x8*)&SM[colL * 72 + rw];
    }
  }
}

// Split-K GEMM (MT=64) -> f32 partials Cp[z][4096][N].
__global__ __launch_bounds__(256, 4) void k_gemm_sk(
    const bf16* __restrict__ A, const bf16* __restrict__ B,
    float* __restrict__ Cp, int N, int K, int Ksplit)
{
  __shared__ __align__(16) bf16 As[64 * 64];
  __shared__ __align__(16) bf16 Bs[128 * 64];
  const int m0 = blockIdx.x * 64, n0 = blockIdx.y * 128;
  const int kbeg = blockIdx.z * Ksplit;
  f32x4 acc[4][2] = {};
  gemm_core_async<64>(A, B, As, Bs, acc, K, m0, n0, kbeg, kbeg + Ksplit);

  const int lane15 = threadIdx.x & 15;
  const int quad   = (threadIdx.x & 63) >> 4;
  const int wave   = threadIdx.x >> 6;
  const int wn     = wave << 5;
  float* Cz = Cp + (size_t)blockIdx.z * 4096 * N;
#pragma unroll
  for (int fm = 0; fm < 4; ++fm)
#pragma unroll
    for (int fn = 0; fn < 2; ++fn) {
      const int col = n0 + wn + fn * 16 + lane15;
#pragma unroll
      for (int r = 0; r < 4; ++r) {
        const int row = m0 + fm * 16 + quad * 4 + r;
        Cz[(size_t)row * N + col] = acc[fm][fn][r];
      }
    }
}

// ---------------------------------------------------------------------------
// Flash attention, split-K x4, 32 q-rows/wave, async K/V staging (swizzled,
// no pad). No online max (bounded scores); l via ones-MFMA; P round-trips
// LDS bf16 (wave-private).
//
// R2 changes (R1 regressed -> reverted to R0 two-barrier flow, then):
//  * P layout: pitch 72 (keeps reads 16B-aligned + conflict-free-minimal),
//    writes de-conflicted via col XOR swizzle col' = col ^ (((row>>2)&3)<<3):
//    write banks become 4 disjoint 8-spans (2 lanes/bank = free); read key
//    recovered as lane15>>2, block stays 8-col-contiguous (b128-aligned).
//  * mask double-buffer: mw(kt+1) loaded into registers right after the
//    barrier -> mask-load latency hides under full tile, P-store no longer
//    stalls on vmcnt for masks.
//  * exp folded to a single v_exp_f32: exp2(s * 0.125*log2e).
//  * O epilogue round-trips LDS (same swizzle) -> full 128B-line stores,
//    kills partial-line write amplification on Opart.
// ---------------------------------------------------------------------------
__global__ __launch_bounds__(256, 4) void k_attn(
    const bf16* __restrict__ Q, const bf16* __restrict__ Km,
    const bf16* __restrict__ Vt, const unsigned long long* __restrict__ mb,
    bf16* __restrict__ Opart, float* __restrict__ Lpart)
{
  constexpr int PP = 72;                       // P pitch (elements)
  __shared__ __align__(16) bf16 Ks[64 * 64];
  __shared__ __align__(16) bf16 Vs[64 * 64];
  __shared__ __align__(16) bf16 Plb[4][32 * PP];

  const int tid    = threadIdx.x;
  const int wave   = tid >> 6;
  const int lane   = tid & 63;
  const int lane15 = lane & 15;
  const int quad   = lane >> 4;
  const int sp     = blockIdx.x & 3;
  const int hd     = (blockIdx.x >> 2) & 7;
  const int qt     = blockIdx.x >> 5;
  const int qrow   = qt * 128 + wave * 32;

  bf16x8 qf[2][2];
#pragma unroll
  for (int mt = 0; mt < 2; ++mt)
#pragma unroll
    for (int c = 0; c < 2; ++c)
      qf[mt][c] = *(const bf16x8*)&Q[(size_t)(qrow + mt * 16 + lane15) * 512 +
                                     hd * 64 + c * 32 + quad * 8];

  // async staging bases (chunk geometry identical to GEMM core, 2 instrs/wave)
  int srK[2], soK[2];
#pragma unroll
  for (int i = 0; i < 2; ++i) {
    int c  = ((wave * 2 + i) << 6) + lane;
    srK[i] = c >> 3;
    soK[i] = ((c & 7) ^ swz(srK[i])) * 8;
  }
  const bf16* KmB[2] = {
      Km + (size_t)srK[0] * 512 + hd * 64 + soK[0],
      Km + (size_t)srK[1] * 512 + hd * 64 + soK[1]};
  const bf16* VtB[2] = {
      Vt + (size_t)(hd * 64 + srK[0]) * 4096 + soK[0],
      Vt + (size_t)(hd * 64 + srK[1]) * 4096 + soK[1]};

  bf16x8 ones;
#pragma unroll
  for (int j = 0; j < 8; ++j) ones[j] = (bf16)1.0f;

  f32x4 o[2][4] = {};
  f32x4 la[2]   = {};

  const int kt0 = sp * 16;

  // mask double-buffer: preload tile kt0
  unsigned long long mwc[2][4], mwn[2][4] = {};
#pragma unroll
  for (int mt = 0; mt < 2; ++mt)
#pragma unroll
    for (int r = 0; r < 4; ++r)
      mwc[mt][r] = mb[(size_t)(qrow + mt * 16 + quad * 4 + r) * 64 + kt0] >> lane15;

  for (int kt = kt0; kt < kt0 + 16; ++kt) {
    const int kb = kt * 64;
#pragma unroll
    for (int i = 0; i < 2; ++i) {
      ASYNC_CP16(KmB[i] + (size_t)kb * 512, &Ks[(wave * 2 + i) * 512]);
      ASYNC_CP16(VtB[i] + kb,               &Vs[(wave * 2 + i) * 512]);
    }
    __syncthreads();

    // prefetch next tile's masks; latency hides under QK+PV
    if (kt + 1 < kt0 + 16) {
#pragma unroll
      for (int mt = 0; mt < 2; ++mt)
#pragma unroll
        for (int r = 0; r < 4; ++r)
          mwn[mt][r] =
              mb[(size_t)(qrow + mt * 16 + quad * 4 + r) * 64 + kt + 1] >> lane15;
    }

#pragma unroll
    for (int g = 0; g < 4; ++g) {
      const int row = g * 16 + lane15;
      bf16x8 k0f = *(const bf16x8*)&Ks[row * 64 + ((quad       ^ swz(row)) * 8)];
      bf16x8 k1f = *(const bf16x8*)&Ks[row * 64 + (((4 + quad) ^ swz(row)) * 8)];
#pragma unroll
      for (int mt = 0; mt < 2; ++mt) {
        f32x4 s = {};
        __builtin_amdgcn_s_setprio(1);
        s = __builtin_amdgcn_mfma_f32_16x16x32_bf16(qf[mt][0], k0f, s, 0, 0, 0);
        s = __builtin_amdgcn_mfma_f32_16x16x32_bf16(qf[mt][1], k1f, s, 0, 0, 0);
        __builtin_amdgcn_s_setprio(0);
#pragma unroll
        for (int r = 0; r < 4; ++r) {
          const bool ok = ((mwc[mt][r] >> (g * 16)) & 1ull) != 0;
          // exp(s/8) = exp2(s * 0.125*log2e); masked lanes write 0
          const float p =
              ok ? __builtin_amdgcn_exp2f(s[r] * 0.18033688f) : 0.0f;
          Plb[wave][(mt * 16 + quad * 4 + r) * PP +
                    ((g * 16 + lane15) ^ (quad << 3))] = (bf16)p;
        }
      }
    }
    // no barrier needed: Plb is wave-private (ds-order within wave)

#pragma unroll
    for (int c2 = 0; c2 < 2; ++c2) {
      bf16x8 vf[4];
#pragma unroll
      for (int g2 = 0; g2 < 4; ++g2) {
        const int row = g2 * 16 + lane15;
        vf[g2] = *(const bf16x8*)&Vs[row * 64 + (((c2 * 4 + quad) ^ swz(row)) * 8)];
      }
#pragma unroll
      for (int mt = 0; mt < 2; ++mt) {
        bf16x8 pa = *(const bf16x8*)&Plb[wave][(mt * 16 + lane15) * PP +
                        ((c2 * 32 + quad * 8) ^ ((lane15 >> 2) << 3))];
        __builtin_amdgcn_s_setprio(1);
        la[mt] = __builtin_amdgcn_mfma_f32_16x16x32_bf16(pa, ones, la[mt], 0, 0, 0);
#pragma unroll
        for (int g2 = 0; g2 < 4; ++g2)
          o[mt][g2] = __builtin_amdgcn_mfma_f32_16x16x32_bf16(pa, vf[g2], o[mt][g2], 0, 0, 0);
        __builtin_amdgcn_s_setprio(0);
      }
    }

#pragma unroll
    for (int mt = 0; mt < 2; ++mt)
#pragma unroll
      for (int r = 0; r < 4; ++r) mwc[mt][r] = mwn[mt][r];
    __syncthreads();
  }

  // epilogue: stage O through LDS (same swizzle) -> full-line coalesced stores
#pragma unroll
  for (int mt = 0; mt < 2; ++mt)
#pragma unroll
    for (int g2 = 0; g2 < 4; ++g2)
#pragma unroll
      for (int r = 0; r < 4; ++r)
        Plb[wave][(mt * 16 + quad * 4 + r) * PP +
                  ((g2 * 16 + lane15) ^ (quad << 3))] = (bf16)o[mt][g2][r];

  bf16* Oz = Opart + (size_t)sp * 4096 * 512;
#pragma unroll
  for (int p = 0; p < 4; ++p) {
    const int rowL = p * 8 + (lane >> 3);
    const int cw   = (lane & 7) * 8;
    *(bf16x8*)&Oz[(size_t)(qrow + rowL) * 512 + hd * 64 + cw] =
        *(const bf16x8*)&Plb[wave][rowL * PP + (cw ^ (((rowL >> 2) & 3) << 3))];
  }

  if (lane15 == 0) {
#pragma unroll
    for (int mt = 0; mt < 2; ++mt)
#pragma unroll
      for (int r = 0; r < 4; ++r)
        Lpart[sp * 32768 + (qrow + mt * 16 + quad * 4 + r) * 8 + hd] = la[mt][r];
  }
}

// Combine attention partials: ctx = (sum_s O_s) / (sum_s l_s).
__global__ __launch_bounds__(256) void k_attn_combine(
    const bf16* __restrict__ Opart, const float* __restrict__ Lpart,
    bf16* __restrict__ ctx)
{
  const int g = blockIdx.x * 256 + threadIdx.x;
  const size_t base = (size_t)g * 8;
  const int row = g >> 6;
  const int hd  = (g & 63) >> 3;
  float acc[8] = {};
  float l = 0.0f;
#pragma unroll
  for (int s = 0; s < 4; ++s) {
    bf16x8 ov = *(const bf16x8*)&Opart[(size_t)s * 4096 * 512 + base];
#pragma unroll
    for (int j = 0; j < 8; ++j) acc[j] += (float)ov[j];
    l += Lpart[s * 32768 + row * 8 + hd];
  }
  const float rl = 1.0f / l;
  bf16x8 y;
#pragma unroll
  for (int j = 0; j < 8; ++j) y[j] = (bf16)(acc[j] * rl);
  *(bf16x8*)(ctx + base) = y;
}

// ---------------------------------------------------------------------------
// Fused: split-K combine + bias + residual + LayerNorm. N=512 fixed.
// ---------------------------------------------------------------------------
template <int F32OUT>
__global__ __launch_bounds__(256) void k_addln_sk(
    const bf16* __restrict__ x, const float* __restrict__ Cp,
    const float* __restrict__ bias,
    const float* __restrict__ gam, const float* __restrict__ bet,
    void* __restrict__ out)
{
  const int wave = threadIdx.x >> 6, lane = threadIdx.x & 63;
  const int row  = blockIdx.x * 4 + wave;
  const size_t base = (size_t)row * 512 + lane * 8;
  const int col = lane * 8;
  bf16x8 xv = *(const bf16x8*)(x + base);
  const float* p0 = Cp + base;
  const float* p1 = Cp + (size_t)4096 * 512 + base;
  f32x4 a0 = *(const f32x4*)p0, a1 = *(const f32x4*)(p0 + 4);
  f32x4 b0 = *(const f32x4*)p1, b1 = *(const f32x4*)(p1 + 4);
  f32x4 c0 = *(const f32x4*)(bias + col), c1 = *(const f32x4*)(bias + col + 4);
  float v[8], s = 0.0f, s2 = 0.0f;
#pragma unroll
  for (int j = 0; j < 4; ++j) {
    v[j]     = (float)xv[j]     + a0[j] + b0[j] + c0[j];
    v[4 + j] = (float)xv[4 + j] + a1[j] + b1[j] + c1[j];
  }
#pragma unroll
  for (int j = 0; j < 8; ++j) { s += v[j]; s2 += v[j] * v[j]; }
#pragma unroll
  for (int d = 1; d < 64; d <<= 1) { s += __shfl_xor(s, d, 64); s2 += __shfl_xor(s2, d, 64); }
  const float mu  = s * (1.0f / 512.0f);
  const float var = s2 * (1.0f / 512.0f) - mu * mu;
  const float rs  = rsqrtf(var + 1e-5f);
  f32x4 g0 = *(const f32x4*)(gam + col), g1 = *(const f32x4*)(gam + col + 4);
  f32x4 e0 = *(const f32x4*)(bet + col), e1 = *(const f32x4*)(bet + col + 4);
  if (F32OUT) {
    float* o = (float*)out + base;
#pragma unroll
    for (int j = 0; j < 4; ++j) {
      o[j]     = ((v[j] - mu) * rs) * g0[j] + e0[j];
      o[4 + j] = ((v[4 + j] - mu) * rs) * g1[j] + e1[j];
    }
  } else {
    bf16x8 ov;
#pragma unroll
    for (int j = 0; j < 4; ++j) {
      ov[j]     = (bf16)(((v[j] - mu) * rs) * g0[j] + e0[j]);
      ov[4 + j] = (bf16)(((v[4 + j] - mu) * rs) * g1[j] + e1[j]);
    }
    *(bf16x8*)((bf16*)out + base) = ov;
  }
}

// ---------------------------------------------------------------------------
extern "C" void kernel_launch(void* const* d_in, const int* in_sizes, int n_in,
                              void* d_out, int out_size, void* d_ws, size_t ws_size,
                              hipStream_t stream)
{
  const int*   adj = (const int*)  d_in[1];
  const float* bq  = (const float*)d_in[3];
  const float* bk  = (const float*)d_in[5];
  const float* bv  = (const float*)d_in[7];
  const float* bo  = (const float*)d_in[9];
  const float* b1  = (const float*)d_in[11];
  const float* b2  = (const float*)d_in[13];
  const float* g1  = (const float*)d_in[14];
  const float* be1 = (const float*)d_in[15];
  const float* g2  = (const float*)d_in[16];
  const float* be2 = (const float*)d_in[17];

  char* ws = (char*)d_ws;
  const size_t MB = 1024 * 1024;

  // bf16 arena. Wq/Wk/Wv are contiguous, forming the concat [1536,512] matrix.
  bf16* hb  = (bf16*)(ws + 0 * MB);                  // 4 MB
  bf16* Wqb = (bf16*)(ws + 4 * MB);                  // concat base
  bf16* Wkb = (bf16*)(ws + 4 * MB + 512 * 1024);
  bf16* Wvb = (bf16*)(ws + 5 * MB);
  bf16* Wob = (bf16*)(ws + 5 * MB + 512 * 1024);
  bf16* W1b = (bf16*)(ws + 6 * MB);                  // 2 MB
  bf16* W2b = (bf16*)(ws + 8 * MB);                  // 2 MB

  // intermediates (lifetime-packed)
  bf16* q    = (bf16*)(ws + 12 * MB);   // dead after attn
  bf16* k    = (bf16*)(ws + 16 * MB);   // dead after attn
  bf16* vt   = (bf16*)(ws + 24 * MB);   // dead after attn
  unsigned long long* mbits = (unsigned long long*)(ws + 28 * MB); // 2 MB
  bf16* ctx  = (bf16*)(ws + 30 * MB);   // dead after Wo sk-gemm
  bf16*  Opart = (bf16*)(ws + 34 * MB); // 16 MB, dead after attn_combine
  float* Lpart = (float*)(ws + 50 * MB);// 0.5 MB
  float* skP   = (float*)(ws + 34 * MB);// 16 MB f32 partials (over Opart)
  bf16* h1   = (bf16*)(ws + 12 * MB);   // over q (dead)
  bf16* ff1  = (bf16*)(ws + 16 * MB);   // 16 MB over k,vt,mbits,ctx (all dead)

  // cast args
  CastArgs ca;
  const int srcIdx[7] = {0, 2, 4, 6, 8, 10, 12};
  bf16* dsts[7] = {hb, Wqb, Wkb, Wvb, Wob, W1b, W2b};
  int cum = 0;
  for (int t = 0; t < 7; ++t) {
    ca.src[t] = (const float*)d_in[srcIdx[t]];
    ca.dst[t] = dsts[t];
    ca.cum[t] = cum;
    cum += in_sizes[srcIdx[t]] / 8;
  }
  ca.cum[7] = cum;

  const dim3 blk(256);

  // 1. prep: packmask (65536 blocks) + cast
  k_prep<<<dim3(65536 + (cum + 255) / 256), blk, 0, stream>>>(adj, mbits, ca, cum);
  // 2. fused QKV (768 blocks); V blocks write vt directly
  k_gemm_qkv<<<dim3(64, 12), blk, 0, stream>>>(hb, Wqb, bq, bk, bv, q, k, vt);
  // 3. flash attention, split-K x4 (1024 blocks) + combine
  k_attn<<<dim3(1024), blk, 0, stream>>>(q, k, vt, mbits, Opart, Lpart);
  k_attn_combine<<<dim3(1024), blk, 0, stream>>>(Opart, Lpart, ctx);
  // 4. output projection split-K x2 (512 blocks) -> fused combine+LN1 -> h1
  k_gemm_sk<<<dim3(64, 4, 2), blk, 0, stream>>>(ctx, Wob, skP, 512, 512, 256);
  k_addln_sk<0><<<dim3(1024), blk, 0, stream>>>(hb, skP, bo, g1, be1, (void*)h1);
  // 5. ff1 = relu(h1 @ W1^T + b1)  (512 blocks)
  k_gemm<<<dim3(32, 16), blk, 0, stream>>>(h1, W1b, b1, ff1, 2048, 512, 1);
  // 6. ff2 split-K x2 (512 blocks) -> fused combine+LN2 -> d_out (fp32)
  k_gemm_sk<<<dim3(64, 4, 2), blk, 0, stream>>>(ff1, W2b, skP, 512, 2048, 1024);
  k_addln_sk<1><<<dim3(1024), blk, 0, stream>>>(h1, skP, b2, g2, be2, d_out);
}

// Round 3
// 297.845 us; speedup vs baseline: 1.0312x; 1.0312x over previous
//
#include <hip/hip_runtime.h>
#include <stdint.h>
#include <stddef.h>

typedef __bf16 bf16;
typedef __bf16 bf16x8 __attribute__((ext_vector_type(8)));
typedef float  f32x4  __attribute__((ext_vector_type(4)));

typedef __attribute__((address_space(3))) void       lds_void;
typedef __attribute__((address_space(1))) const void gbl_cvoid;

#define ASYNC_CP16(g, l) \
  __builtin_amdgcn_global_load_lds((gbl_cvoid*)(g), (lds_void*)(l), 16, 0, 0)

// chunk swizzle: spreads b128 fragment reads across banks (verified round 5)
__device__ __forceinline__ int swz(int r) { return (r & 7) ^ ((r & 8) >> 1); }

// ---------------------------------------------------------------------------
// Prep kernel: blocks [0,65536) pack adjacency(+I) into 64-bit masks;
// blocks [65536, ...) do the batched fp32->bf16 cast.
// ---------------------------------------------------------------------------
struct CastArgs {
  const float* src[7];
  bf16*        dst[7];
  int          cum[8];
};

__global__ __launch_bounds__(256) void k_prep(
    const int* __restrict__ adj, unsigned long long* __restrict__ mb,
    CastArgs a, int total8)
{
  const int bid = blockIdx.x;
  if (bid < 65536) {
    const int gw   = (int)(((unsigned)bid * 256 + threadIdx.x) >> 6);
    const int lane = threadIdx.x & 63;
    const int av   = adj[(size_t)gw * 64 + lane];
    unsigned long long m = __ballot(av != 0);
    const int row = gw >> 6, wc = gw & 63;
    if ((row >> 6) == wc) m |= 1ull << (row & 63);
    if (lane == 0) mb[gw] = m;
  } else {
    const int g = (bid - 65536) * 256 + threadIdx.x;
    if (g >= total8) return;
    int t = 0;
    while (a.cum[t + 1] <= g) ++t;
    const int i = g - a.cum[t];
    const float4* s = (const float4*)(a.src[t]) + (size_t)i * 2;
    const float4 x0 = s[0], x1 = s[1];
    bf16x8 y;
    y[0] = (bf16)x0.x; y[1] = (bf16)x0.y; y[2] = (bf16)x0.z; y[3] = (bf16)x0.w;
    y[4] = (bf16)x1.x; y[5] = (bf16)x1.y; y[6] = (bf16)x1.z; y[7] = (bf16)x1.w;
    *(bf16x8*)(a.dst[t] + (size_t)i * 8) = y;
  }
}

// ---------------------------------------------------------------------------
// Async-staged GEMM core, templated on m-tile (MT=128: 2x2 waves, 4x4 frags;
// MT=64: 1x4 waves, 4x2 frags). N-tile fixed 128, BK=64.
// ---------------------------------------------------------------------------
template <int MT>
__device__ __forceinline__ void gemm_core_async(
    const bf16* __restrict__ A, const bf16* __restrict__ B,
    bf16* As, bf16* Bs, f32x4 (&acc)[4][(MT == 128) ? 4 : 2],
    int K, int m0, int n0, int kbeg, int kend)
{
  constexpr int FN = (MT == 128) ? 4 : 2;
  constexpr int IA = MT / 32;             // A staging wave-instrs per wave
  const int tid    = threadIdx.x;
  const int lane   = tid & 63;
  const int wave   = tid >> 6;
  const int lane15 = lane & 15;
  const int quad   = lane >> 4;
  const int wm     = (MT == 128) ? ((wave & 1) << 6) : 0;
  const int wn     = (MT == 128) ? ((wave >> 1) << 6) : (wave << 5);

  int srA[IA], soA[IA], srB[4], soB[4];
#pragma unroll
  for (int i = 0; i < IA; ++i) {
    int c  = ((wave * IA + i) << 6) + lane;
    srA[i] = c >> 3;
    soA[i] = ((c & 7) ^ swz(srA[i])) * 8;
  }
#pragma unroll
  for (int i = 0; i < 4; ++i) {
    int c  = ((wave * 4 + i) << 6) + lane;
    srB[i] = c >> 3;
    soB[i] = ((c & 7) ^ swz(srB[i])) * 8;
  }

  const bf16* Ab = A + (size_t)m0 * K;
  const bf16* Bb = B + (size_t)n0 * K;

  for (int k0 = kbeg; k0 < kend; k0 += 64) {
#pragma unroll
    for (int i = 0; i < IA; ++i)
      ASYNC_CP16(Ab + (size_t)srA[i] * K + k0 + soA[i], &As[(wave * IA + i) * 512]);
#pragma unroll
    for (int i = 0; i < 4; ++i)
      ASYNC_CP16(Bb + (size_t)srB[i] * K + k0 + soB[i], &Bs[(wave * 4 + i) * 512]);
    __syncthreads();

#pragma unroll
    for (int kk = 0; kk < 2; ++kk) {
      bf16x8 af[4], bfr[FN];
#pragma unroll
      for (int f = 0; f < 4; ++f) {
        const int ra = wm + f * 16 + lane15;
        af[f] = *(const bf16x8*)&As[ra * 64 + (((kk * 4 + quad) ^ swz(ra)) * 8)];
      }
#pragma unroll
      for (int f = 0; f < FN; ++f) {
        const int rb = wn + f * 16 + lane15;
        bfr[f] = *(const bf16x8*)&Bs[rb * 64 + (((kk * 4 + quad) ^ swz(rb)) * 8)];
      }
#pragma unroll
      for (int fm = 0; fm < 4; ++fm)
#pragma unroll
        for (int fn = 0; fn < FN; ++fn)
          acc[fm][fn] = __builtin_amdgcn_mfma_f32_16x16x32_bf16(
              af[fm], bfr[fn], acc[fm][fn], 0, 0, 0);
    }
    __syncthreads();
  }
}

// FF1: MT=128 full-K GEMM + bias + relu.
__global__ __launch_bounds__(256, 2) void k_gemm(
    const bf16* __restrict__ A, const bf16* __restrict__ B,
    const float* __restrict__ bias, bf16* __restrict__ C,
    int N, int K, int relu)
{
  __shared__ __align__(16) bf16 As[128 * 64];
  __shared__ __align__(16) bf16 Bs[128 * 64];
  const int m0 = blockIdx.x * 128, n0 = blockIdx.y * 128;
  f32x4 acc[4][4] = {};
  gemm_core_async<128>(A, B, As, Bs, acc, K, m0, n0, 0, K);

  const int lane15 = threadIdx.x & 15;
  const int quad   = (threadIdx.x & 63) >> 4;
  const int wave   = threadIdx.x >> 6;
  const int wm = (wave & 1) << 6, wn = (wave >> 1) << 6;
#pragma unroll
  for (int fm = 0; fm < 4; ++fm)
#pragma unroll
    for (int fn = 0; fn < 4; ++fn) {
      const int col = n0 + wn + fn * 16 + lane15;
      const float bv = bias[col];
#pragma unroll
      for (int r = 0; r < 4; ++r) {
        const int row = m0 + wm + fm * 16 + quad * 4 + r;
        float v = acc[fm][fn][r] + bv;
        if (relu) v = fmaxf(v, 0.0f);
        C[(size_t)row * N + col] = (bf16)v;
      }
    }
}

// QKV: one GEMM over concat weights [1536,512] (rows 0-511 Wq, 512-1023 Wk,
// 1024-1535 Wv). MT=64 -> grid (64,12) = 768 blocks. V-projection blocks
// write vt (transposed) via an LDS transpose in the epilogue.
__global__ __launch_bounds__(256, 4) void k_gemm_qkv(
    const bf16* __restrict__ h, const bf16* __restrict__ Wcat,
    const float* __restrict__ bq, const float* __restrict__ bk,
    const float* __restrict__ bv,
    bf16* __restrict__ q, bf16* __restrict__ k, bf16* __restrict__ vt)
{
  __shared__ __align__(16) bf16 SM[64 * 64 + 128 * 64];   // 24 KB
  bf16* As = SM;
  bf16* Bs = SM + 64 * 64;
  const int m0 = blockIdx.x * 64, n0 = blockIdx.y * 128;
  f32x4 acc[4][2] = {};
  gemm_core_async<64>(h, Wcat, As, Bs, acc, 512, m0, n0, 0, 512);

  const int lane15 = threadIdx.x & 15;
  const int quad   = (threadIdx.x & 63) >> 4;
  const int wave   = threadIdx.x >> 6;
  const int wn     = wave << 5;
  const int proj   = n0 >> 9;                  // 0=q 1=k 2=v
  const int ncol0  = n0 & 511;
  const float* bias = (proj == 0) ? bq : (proj == 1) ? bk : bv;

  if (proj < 2) {
    bf16* C = proj ? k : q;
#pragma unroll
    for (int fm = 0; fm < 4; ++fm)
#pragma unroll
      for (int fn = 0; fn < 2; ++fn) {
        const int col = ncol0 + wn + fn * 16 + lane15;
        const float bvv = bias[col];
#pragma unroll
        for (int r = 0; r < 4; ++r) {
          const int row = m0 + fm * 16 + quad * 4 + r;
          C[(size_t)row * 512 + col] = (bf16)(acc[fm][fn][r] + bvv);
        }
      }
  } else {
    // transpose 64(tokens) x 128(vdims) through LDS -> vt[vdim][token]
    __syncthreads();   // K-loop LDS dead
#pragma unroll
    for (int fm = 0; fm < 4; ++fm)
#pragma unroll
      for (int fn = 0; fn < 2; ++fn) {
        const int colL = wn + fn * 16 + lane15;
        const float bvv = bias[ncol0 + colL];
#pragma unroll
        for (int r = 0; r < 4; ++r) {
          const int rowL = fm * 16 + quad * 4 + r;
          SM[colL * 72 + rowL] = (bf16)(acc[fm][fn][r] + bvv);
        }
      }
    __syncthreads();
#pragma unroll
    for (int i = 0; i < 4; ++i) {
      const int c = i * 256 + threadIdx.x;     // 1024 chunks
      const int colL = c >> 3, rw = (c & 7) * 8;
      *(bf16x8*)&vt[(size_t)(ncol0 + colL) * 4096 + m0 + rw] =
          *(const bf16x8*)&SM[colL * 72 + rw];
    }
  }
}

// Split-K GEMM (MT=64) -> f32 partials Cp[z][4096][N].
__global__ __launch_bounds__(256, 4) void k_gemm_sk(
    const bf16* __restrict__ A, const bf16* __restrict__ B,
    float* __restrict__ Cp, int N, int K, int Ksplit)
{
  __shared__ __align__(16) bf16 As[64 * 64];
  __shared__ __align__(16) bf16 Bs[128 * 64];
  const int m0 = blockIdx.x * 64, n0 = blockIdx.y * 128;
  const int kbeg = blockIdx.z * Ksplit;
  f32x4 acc[4][2] = {};
  gemm_core_async<64>(A, B, As, Bs, acc, K, m0, n0, kbeg, kbeg + Ksplit);

  const int lane15 = threadIdx.x & 15;
  const int quad   = (threadIdx.x & 63) >> 4;
  const int wave   = threadIdx.x >> 6;
  const int wn     = wave << 5;
  float* Cz = Cp + (size_t)blockIdx.z * 4096 * N;
#pragma unroll
  for (int fm = 0; fm < 4; ++fm)
#pragma unroll
    for (int fn = 0; fn < 2; ++fn) {
      const int col = n0 + wn + fn * 16 + lane15;
#pragma unroll
      for (int r = 0; r < 4; ++r) {
        const int row = m0 + fm * 16 + quad * 4 + r;
        Cz[(size_t)row * N + col] = acc[fm][fn][r];
      }
    }
}

// ---------------------------------------------------------------------------
// Flash attention, split-K x4. R3: 512 threads = 8 waves x 16 q-rows (was
// 4 x 32). Total work per block identical; per-wave register state halves;
// occupancy target 24-32 waves/CU (was 16) to cover the dependency stalls
// the R0 counters showed (28% issue utilization, no pipe >52%).
// R1/R2 scheduling experiments reverted (both regressed via spills/traffic):
// in-loop mask loads, plain pitch-72 P stores, R0 scalar epilogue.
// ---------------------------------------------------------------------------
__global__ __launch_bounds__(512, 6) void k_attn(
    const bf16* __restrict__ Q, const bf16* __restrict__ Km,
    const bf16* __restrict__ Vt, const unsigned long long* __restrict__ mb,
    bf16* __restrict__ Opart, float* __restrict__ Lpart)
{
  constexpr int PP = 72;                       // P pitch (elements)
  __shared__ __align__(16) bf16 Ks[64 * 64];
  __shared__ __align__(16) bf16 Vs[64 * 64];
  __shared__ __align__(16) bf16 Plb[8][16 * PP];

  const int tid    = threadIdx.x;
  const int wave   = tid >> 6;
  const int lane   = tid & 63;
  const int lane15 = lane & 15;
  const int quad   = lane >> 4;
  const int sp     = blockIdx.x & 3;
  const int hd     = (blockIdx.x >> 2) & 7;
  const int qt     = blockIdx.x >> 5;
  const int qrow   = qt * 128 + wave * 16;     // 16 rows per wave

  bf16x8 qf[2];
#pragma unroll
  for (int c = 0; c < 2; ++c)
    qf[c] = *(const bf16x8*)&Q[(size_t)(qrow + lane15) * 512 +
                               hd * 64 + c * 32 + quad * 8];

  // staging: one 1KB K-chunk + one 1KB V-chunk per wave (8 waves = 8 chunks)
  const int cch = (wave << 6) + lane;
  const int sr  = cch >> 3;                    // row 0..63
  const int so  = ((cch & 7) ^ swz(sr)) * 8;
  const bf16* KmB = Km + (size_t)sr * 512 + hd * 64 + so;
  const bf16* VtB = Vt + (size_t)(hd * 64 + sr) * 4096 + so;

  bf16x8 ones;
#pragma unroll
  for (int j = 0; j < 8; ++j) ones[j] = (bf16)1.0f;

  f32x4 o[4] = {};
  f32x4 la   = {};

  const int kt0 = sp * 16;
  const unsigned long long* mbw = mb + (size_t)(qrow + quad * 4) * 64;

  for (int kt = kt0; kt < kt0 + 16; ++kt) {
    const int kb = kt * 64;
    ASYNC_CP16(KmB + (size_t)kb * 512, &Ks[wave * 512]);
    ASYNC_CP16(VtB + kb,               &Vs[wave * 512]);
    __syncthreads();

    unsigned long long mwc[4];
#pragma unroll
    for (int r = 0; r < 4; ++r)
      mwc[r] = mbw[r * 64 + kt] >> lane15;

#pragma unroll
    for (int g = 0; g < 4; ++g) {
      const int row = g * 16 + lane15;
      bf16x8 k0f = *(const bf16x8*)&Ks[row * 64 + ((quad       ^ swz(row)) * 8)];
      bf16x8 k1f = *(const bf16x8*)&Ks[row * 64 + (((4 + quad) ^ swz(row)) * 8)];
      f32x4 s = {};
      __builtin_amdgcn_s_setprio(1);
      s = __builtin_amdgcn_mfma_f32_16x16x32_bf16(qf[0], k0f, s, 0, 0, 0);
      s = __builtin_amdgcn_mfma_f32_16x16x32_bf16(qf[1], k1f, s, 0, 0, 0);
      __builtin_amdgcn_s_setprio(0);
#pragma unroll
      for (int r = 0; r < 4; ++r) {
        const bool ok = ((mwc[r] >> (g * 16)) & 1ull) != 0;
        // exp(s/8) = exp2(s * 0.125*log2e)
        const float p = ok ? __builtin_amdgcn_exp2f(s[r] * 0.18033688f) : 0.0f;
        Plb[wave][(quad * 4 + r) * PP + g * 16 + lane15] = (bf16)p;
      }
    }
    // Plb is wave-private; in-wave ds write->read needs no barrier

#pragma unroll
    for (int c2 = 0; c2 < 2; ++c2) {
      bf16x8 vf[4];
#pragma unroll
      for (int g2 = 0; g2 < 4; ++g2) {
        const int row = g2 * 16 + lane15;
        vf[g2] = *(const bf16x8*)&Vs[row * 64 + (((c2 * 4 + quad) ^ swz(row)) * 8)];
      }
      bf16x8 pa = *(const bf16x8*)&Plb[wave][lane15 * PP + c2 * 32 + quad * 8];
      __builtin_amdgcn_s_setprio(1);
      la = __builtin_amdgcn_mfma_f32_16x16x32_bf16(pa, ones, la, 0, 0, 0);
#pragma unroll
      for (int g2 = 0; g2 < 4; ++g2)
        o[g2] = __builtin_amdgcn_mfma_f32_16x16x32_bf16(pa, vf[g2], o[g2], 0, 0, 0);
      __builtin_amdgcn_s_setprio(0);
    }
    __syncthreads();
  }

  bf16* Oz = Opart + (size_t)sp * 4096 * 512;
#pragma unroll
  for (int g2 = 0; g2 < 4; ++g2)
#pragma unroll
    for (int r = 0; r < 4; ++r) {
      const int row = qrow + quad * 4 + r;
      Oz[(size_t)row * 512 + hd * 64 + g2 * 16 + lane15] = (bf16)o[g2][r];
    }
  if (lane15 == 0) {
#pragma unroll
    for (int r = 0; r < 4; ++r)
      Lpart[sp * 32768 + (qrow + quad * 4 + r) * 8 + hd] = la[r];
  }
}

// Combine attention partials: ctx = (sum_s O_s) / (sum_s l_s).
__global__ __launch_bounds__(256) void k_attn_combine(
    const bf16* __restrict__ Opart, const float* __restrict__ Lpart,
    bf16* __restrict__ ctx)
{
  const int g = blockIdx.x * 256 + threadIdx.x;
  const size_t base = (size_t)g * 8;
  const int row = g >> 6;
  const int hd  = (g & 63) >> 3;
  float acc[8] = {};
  float l = 0.0f;
#pragma unroll
  for (int s = 0; s < 4; ++s) {
    bf16x8 ov = *(const bf16x8*)&Opart[(size_t)s * 4096 * 512 + base];
#pragma unroll
    for (int j = 0; j < 8; ++j) acc[j] += (float)ov[j];
    l += Lpart[s * 32768 + row * 8 + hd];
  }
  const float rl = 1.0f / l;
  bf16x8 y;
#pragma unroll
  for (int j = 0; j < 8; ++j) y[j] = (bf16)(acc[j] * rl);
  *(bf16x8*)(ctx + base) = y;
}

// ---------------------------------------------------------------------------
// Fused: split-K combine + bias + residual + LayerNorm. N=512 fixed.
// ---------------------------------------------------------------------------
template <int F32OUT>
__global__ __launch_bounds__(256) void k_addln_sk(
    const bf16* __restrict__ x, const float* __restrict__ Cp,
    const float* __restrict__ bias,
    const float* __restrict__ gam, const float* __restrict__ bet,
    void* __restrict__ out)
{
  const int wave = threadIdx.x >> 6, lane = threadIdx.x & 63;
  const int row  = blockIdx.x * 4 + wave;
  const size_t base = (size_t)row * 512 + lane * 8;
  const int col = lane * 8;
  bf16x8 xv = *(const bf16x8*)(x + base);
  const float* p0 = Cp + base;
  const float* p1 = Cp + (size_t)4096 * 512 + base;
  f32x4 a0 = *(const f32x4*)p0, a1 = *(const f32x4*)(p0 + 4);
  f32x4 b0 = *(const f32x4*)p1, b1 = *(const f32x4*)(p1 + 4);
  f32x4 c0 = *(const f32x4*)(bias + col), c1 = *(const f32x4*)(bias + col + 4);
  float v[8], s = 0.0f, s2 = 0.0f;
#pragma unroll
  for (int j = 0; j < 4; ++j) {
    v[j]     = (float)xv[j]     + a0[j] + b0[j] + c0[j];
    v[4 + j] = (float)xv[4 + j] + a1[j] + b1[j] + c1[j];
  }
#pragma unroll
  for (int j = 0; j < 8; ++j) { s += v[j]; s2 += v[j] * v[j]; }
#pragma unroll
  for (int d = 1; d < 64; d <<= 1) { s += __shfl_xor(s, d, 64); s2 += __shfl_xor(s2, d, 64); }
  const float mu  = s * (1.0f / 512.0f);
  const float var = s2 * (1.0f / 512.0f) - mu * mu;
  const float rs  = rsqrtf(var + 1e-5f);
  f32x4 g0 = *(const f32x4*)(gam + col), g1 = *(const f32x4*)(gam + col + 4);
  f32x4 e0 = *(const f32x4*)(bet + col), e1 = *(const f32x4*)(bet + col + 4);
  if (F32OUT) {
    float* o = (float*)out + base;
#pragma unroll
    for (int j = 0; j < 4; ++j) {
      o[j]     = ((v[j] - mu) * rs) * g0[j] + e0[j];
      o[4 + j] = ((v[4 + j] - mu) * rs) * g1[j] + e1[j];
    }
  } else {
    bf16x8 ov;
#pragma unroll
    for (int j = 0; j < 4; ++j) {
      ov[j]     = (bf16)(((v[j] - mu) * rs) * g0[j] + e0[j]);
      ov[4 + j] = (bf16)(((v[4 + j] - mu) * rs) * g1[j] + e1[j]);
    }
    *(bf16x8*)((bf16*)out + base) = ov;
  }
}

// ---------------------------------------------------------------------------
extern "C" void kernel_launch(void* const* d_in, const int* in_sizes, int n_in,
                              void* d_out, int out_size, void* d_ws, size_t ws_size,
                              hipStream_t stream)
{
  const int*   adj = (const int*)  d_in[1];
  const float* bq  = (const float*)d_in[3];
  const float* bk  = (const float*)d_in[5];
  const float* bv  = (const float*)d_in[7];
  const float* bo  = (const float*)d_in[9];
  const float* b1  = (const float*)d_in[11];
  const float* b2  = (const float*)d_in[13];
  const float* g1  = (const float*)d_in[14];
  const float* be1 = (const float*)d_in[15];
  const float* g2  = (const float*)d_in[16];
  const float* be2 = (const float*)d_in[17];

  char* ws = (char*)d_ws;
  const size_t MB = 1024 * 1024;

  // bf16 arena. Wq/Wk/Wv are contiguous, forming the concat [1536,512] matrix.
  bf16* hb  = (bf16*)(ws + 0 * MB);                  // 4 MB
  bf16* Wqb = (bf16*)(ws + 4 * MB);                  // concat base
  bf16* Wkb = (bf16*)(ws + 4 * MB + 512 * 1024);
  bf16* Wvb = (bf16*)(ws + 5 * MB);
  bf16* Wob = (bf16*)(ws + 5 * MB + 512 * 1024);
  bf16* W1b = (bf16*)(ws + 6 * MB);                  // 2 MB
  bf16* W2b = (bf16*)(ws + 8 * MB);                  // 2 MB

  // intermediates (lifetime-packed)
  bf16* q    = (bf16*)(ws + 12 * MB);   // dead after attn
  bf16* k    = (bf16*)(ws + 16 * MB);   // dead after attn
  bf16* vt   = (bf16*)(ws + 24 * MB);   // dead after attn
  unsigned long long* mbits = (unsigned long long*)(ws + 28 * MB); // 2 MB
  bf16* ctx  = (bf16*)(ws + 30 * MB);   // dead after Wo sk-gemm
  bf16*  Opart = (bf16*)(ws + 34 * MB); // 16 MB, dead after attn_combine
  float* Lpart = (float*)(ws + 50 * MB);// 0.5 MB
  float* skP   = (float*)(ws + 34 * MB);// 16 MB f32 partials (over Opart)
  bf16* h1   = (bf16*)(ws + 12 * MB);   // over q (dead)
  bf16* ff1  = (bf16*)(ws + 16 * MB);   // 16 MB over k,vt,mbits,ctx (all dead)

  // cast args
  CastArgs ca;
  const int srcIdx[7] = {0, 2, 4, 6, 8, 10, 12};
  bf16* dsts[7] = {hb, Wqb, Wkb, Wvb, Wob, W1b, W2b};
  int cum = 0;
  for (int t = 0; t < 7; ++t) {
    ca.src[t] = (const float*)d_in[srcIdx[t]];
    ca.dst[t] = dsts[t];
    ca.cum[t] = cum;
    cum += in_sizes[srcIdx[t]] / 8;
  }
  ca.cum[7] = cum;

  const dim3 blk(256);

  // 1. prep: packmask (65536 blocks) + cast
  k_prep<<<dim3(65536 + (cum + 255) / 256), blk, 0, stream>>>(adj, mbits, ca, cum);
  // 2. fused QKV (768 blocks); V blocks write vt directly
  k_gemm_qkv<<<dim3(64, 12), blk, 0, stream>>>(hb, Wqb, bq, bk, bv, q, k, vt);
  // 3. flash attention, split-K x4 (1024 blocks x 512 threads) + combine
  k_attn<<<dim3(1024), dim3(512), 0, stream>>>(q, k, vt, mbits, Opart, Lpart);
  k_attn_combine<<<dim3(1024), blk, 0, stream>>>(Opart, Lpart, ctx);
  // 4. output projection split-K x2 (512 blocks) -> fused combine+LN1 -> h1
  k_gemm_sk<<<dim3(64, 4, 2), blk, 0, stream>>>(ctx, Wob, skP, 512, 512, 256);
  k_addln_sk<0><<<dim3(1024), blk, 0, stream>>>(hb, skP, bo, g1, be1, (void*)h1);
  // 5. ff1 = relu(h1 @ W1^T + b1)  (512 blocks)
  k_gemm<<<dim3(32, 16), blk, 0, stream>>>(h1, W1b, b1, ff1, 2048, 512, 1);
  // 6. ff2 split-K x2 (512 blocks) -> fused combine+LN2 -> d_out (fp32)
  k_gemm_sk<<<dim3(64, 4, 2), blk, 0, stream>>>(ff1, W2b, skP, 512, 2048, 1024);
  k_addln_sk<1><<<dim3(1024), blk, 0, stream>>>(h1, skP, b2, g2, be2, d_out);
}

// Round 4
// 295.707 us; speedup vs baseline: 1.0386x; 1.0072x over previous
//
#include <hip/hip_runtime.h>
#include <stdint.h>
#include <stddef.h>

typedef __bf16 bf16;
typedef __bf16 bf16x8 __attribute__((ext_vector_type(8)));
typedef float  f32x4  __attribute__((ext_vector_type(4)));

typedef __attribute__((address_space(3))) void       lds_void;
typedef __attribute__((address_space(1))) const void gbl_cvoid;

#define ASYNC_CP16(g, l) \
  __builtin_amdgcn_global_load_lds((gbl_cvoid*)(g), (lds_void*)(l), 16, 0, 0)

// chunk swizzle: spreads b128 fragment reads across banks (verified round 5)
__device__ __forceinline__ int swz(int r) { return (r & 7) ^ ((r & 8) >> 1); }

// ---------------------------------------------------------------------------
// Prep kernel: blocks [0,65536) pack adjacency(+I) into 64-bit masks;
// blocks [65536, ...) do the batched fp32->bf16 cast.
// ---------------------------------------------------------------------------
struct CastArgs {
  const float* src[7];
  bf16*        dst[7];
  int          cum[8];
};

__global__ __launch_bounds__(256) void k_prep(
    const int* __restrict__ adj, unsigned long long* __restrict__ mb,
    CastArgs a, int total8)
{
  const int bid = blockIdx.x;
  if (bid < 65536) {
    const int gw   = (int)(((unsigned)bid * 256 + threadIdx.x) >> 6);
    const int lane = threadIdx.x & 63;
    const int av   = adj[(size_t)gw * 64 + lane];
    unsigned long long m = __ballot(av != 0);
    const int row = gw >> 6, wc = gw & 63;
    if ((row >> 6) == wc) m |= 1ull << (row & 63);
    if (lane == 0) mb[gw] = m;
  } else {
    const int g = (bid - 65536) * 256 + threadIdx.x;
    if (g >= total8) return;
    int t = 0;
    while (a.cum[t + 1] <= g) ++t;
    const int i = g - a.cum[t];
    const float4* s = (const float4*)(a.src[t]) + (size_t)i * 2;
    const float4 x0 = s[0], x1 = s[1];
    bf16x8 y;
    y[0] = (bf16)x0.x; y[1] = (bf16)x0.y; y[2] = (bf16)x0.z; y[3] = (bf16)x0.w;
    y[4] = (bf16)x1.x; y[5] = (bf16)x1.y; y[6] = (bf16)x1.z; y[7] = (bf16)x1.w;
    *(bf16x8*)(a.dst[t] + (size_t)i * 8) = y;
  }
}

// ---------------------------------------------------------------------------
// Async-staged GEMM core, templated on m-tile (MT=128: 2x2 waves, 4x4 frags;
// MT=64: 1x4 waves, 4x2 frags). N-tile fixed 128, BK=64.
// ---------------------------------------------------------------------------
template <int MT>
__device__ __forceinline__ void gemm_core_async(
    const bf16* __restrict__ A, const bf16* __restrict__ B,
    bf16* As, bf16* Bs, f32x4 (&acc)[4][(MT == 128) ? 4 : 2],
    int K, int m0, int n0, int kbeg, int kend)
{
  constexpr int FN = (MT == 128) ? 4 : 2;
  constexpr int IA = MT / 32;             // A staging wave-instrs per wave
  const int tid    = threadIdx.x;
  const int lane   = tid & 63;
  const int wave   = tid >> 6;
  const int lane15 = lane & 15;
  const int quad   = lane >> 4;
  const int wm     = (MT == 128) ? ((wave & 1) << 6) : 0;
  const int wn     = (MT == 128) ? ((wave >> 1) << 6) : (wave << 5);

  int srA[IA], soA[IA], srB[4], soB[4];
#pragma unroll
  for (int i = 0; i < IA; ++i) {
    int c  = ((wave * IA + i) << 6) + lane;
    srA[i] = c >> 3;
    soA[i] = ((c & 7) ^ swz(srA[i])) * 8;
  }
#pragma unroll
  for (int i = 0; i < 4; ++i) {
    int c  = ((wave * 4 + i) << 6) + lane;
    srB[i] = c >> 3;
    soB[i] = ((c & 7) ^ swz(srB[i])) * 8;
  }

  const bf16* Ab = A + (size_t)m0 * K;
  const bf16* Bb = B + (size_t)n0 * K;

  for (int k0 = kbeg; k0 < kend; k0 += 64) {
#pragma unroll
    for (int i = 0; i < IA; ++i)
      ASYNC_CP16(Ab + (size_t)srA[i] * K + k0 + soA[i], &As[(wave * IA + i) * 512]);
#pragma unroll
    for (int i = 0; i < 4; ++i)
      ASYNC_CP16(Bb + (size_t)srB[i] * K + k0 + soB[i], &Bs[(wave * 4 + i) * 512]);
    __syncthreads();

#pragma unroll
    for (int kk = 0; kk < 2; ++kk) {
      bf16x8 af[4], bfr[FN];
#pragma unroll
      for (int f = 0; f < 4; ++f) {
        const int ra = wm + f * 16 + lane15;
        af[f] = *(const bf16x8*)&As[ra * 64 + (((kk * 4 + quad) ^ swz(ra)) * 8)];
      }
#pragma unroll
      for (int f = 0; f < FN; ++f) {
        const int rb = wn + f * 16 + lane15;
        bfr[f] = *(const bf16x8*)&Bs[rb * 64 + (((kk * 4 + quad) ^ swz(rb)) * 8)];
      }
#pragma unroll
      for (int fm = 0; fm < 4; ++fm)
#pragma unroll
        for (int fn = 0; fn < FN; ++fn)
          acc[fm][fn] = __builtin_amdgcn_mfma_f32_16x16x32_bf16(
              af[fm], bfr[fn], acc[fm][fn], 0, 0, 0);
    }
    __syncthreads();
  }
}

// FF1: MT=128 full-K GEMM + bias + relu.
__global__ __launch_bounds__(256, 2) void k_gemm(
    const bf16* __restrict__ A, const bf16* __restrict__ B,
    const float* __restrict__ bias, bf16* __restrict__ C,
    int N, int K, int relu)
{
  __shared__ __align__(16) bf16 As[128 * 64];
  __shared__ __align__(16) bf16 Bs[128 * 64];
  const int m0 = blockIdx.x * 128, n0 = blockIdx.y * 128;
  f32x4 acc[4][4] = {};
  gemm_core_async<128>(A, B, As, Bs, acc, K, m0, n0, 0, K);

  const int lane15 = threadIdx.x & 15;
  const int quad   = (threadIdx.x & 63) >> 4;
  const int wave   = threadIdx.x >> 6;
  const int wm = (wave & 1) << 6, wn = (wave >> 1) << 6;
#pragma unroll
  for (int fm = 0; fm < 4; ++fm)
#pragma unroll
    for (int fn = 0; fn < 4; ++fn) {
      const int col = n0 + wn + fn * 16 + lane15;
      const float bv = bias[col];
#pragma unroll
      for (int r = 0; r < 4; ++r) {
        const int row = m0 + wm + fm * 16 + quad * 4 + r;
        float v = acc[fm][fn][r] + bv;
        if (relu) v = fmaxf(v, 0.0f);
        C[(size_t)row * N + col] = (bf16)v;
      }
    }
}

// QKV: one GEMM over concat weights [1536,512] (rows 0-511 Wq, 512-1023 Wk,
// 1024-1535 Wv). MT=64 -> grid (64,12) = 768 blocks. V-projection blocks
// write vt (transposed) via an LDS transpose in the epilogue.
__global__ __launch_bounds__(256, 4) void k_gemm_qkv(
    const bf16* __restrict__ h, const bf16* __restrict__ Wcat,
    const float* __restrict__ bq, const float* __restrict__ bk,
    const float* __restrict__ bv,
    bf16* __restrict__ q, bf16* __restrict__ k, bf16* __restrict__ vt)
{
  __shared__ __align__(16) bf16 SM[64 * 64 + 128 * 64];   // 24 KB
  bf16* As = SM;
  bf16* Bs = SM + 64 * 64;
  const int m0 = blockIdx.x * 64, n0 = blockIdx.y * 128;
  f32x4 acc[4][2] = {};
  gemm_core_async<64>(h, Wcat, As, Bs, acc, 512, m0, n0, 0, 512);

  const int lane15 = threadIdx.x & 15;
  const int quad   = (threadIdx.x & 63) >> 4;
  const int wave   = threadIdx.x >> 6;
  const int wn     = wave << 5;
  const int proj   = n0 >> 9;                  // 0=q 1=k 2=v
  const int ncol0  = n0 & 511;
  const float* bias = (proj == 0) ? bq : (proj == 1) ? bk : bv;

  if (proj < 2) {
    bf16* C = proj ? k : q;
#pragma unroll
    for (int fm = 0; fm < 4; ++fm)
#pragma unroll
      for (int fn = 0; fn < 2; ++fn) {
        const int col = ncol0 + wn + fn * 16 + lane15;
        const float bvv = bias[col];
#pragma unroll
        for (int r = 0; r < 4; ++r) {
          const int row = m0 + fm * 16 + quad * 4 + r;
          C[(size_t)row * 512 + col] = (bf16)(acc[fm][fn][r] + bvv);
        }
      }
  } else {
    // transpose 64(tokens) x 128(vdims) through LDS -> vt[vdim][token]
    __syncthreads();   // K-loop LDS dead
#pragma unroll
    for (int fm = 0; fm < 4; ++fm)
#pragma unroll
      for (int fn = 0; fn < 2; ++fn) {
        const int colL = wn + fn * 16 + lane15;
        const float bvv = bias[ncol0 + colL];
#pragma unroll
        for (int r = 0; r < 4; ++r) {
          const int rowL = fm * 16 + quad * 4 + r;
          SM[colL * 72 + rowL] = (bf16)(acc[fm][fn][r] + bvv);
        }
      }
    __syncthreads();
#pragma unroll
    for (int i = 0; i < 4; ++i) {
      const int c = i * 256 + threadIdx.x;     // 1024 chunks
      const int colL = c >> 3, rw = (c & 7) * 8;
      *(bf16x8*)&vt[(size_t)(ncol0 + colL) * 4096 + m0 + rw] =
          *(const bf16x8*)&SM[colL * 72 + rw];
    }
  }
}

// Split-K GEMM (MT=64) -> f32 partials Cp[z][4096][N].
__global__ __launch_bounds__(256, 4) void k_gemm_sk(
    const bf16* __restrict__ A, const bf16* __restrict__ B,
    float* __restrict__ Cp, int N, int K, int Ksplit)
{
  __shared__ __align__(16) bf16 As[64 * 64];
  __shared__ __align__(16) bf16 Bs[128 * 64];
  const int m0 = blockIdx.x * 64, n0 = blockIdx.y * 128;
  const int kbeg = blockIdx.z * Ksplit;
  f32x4 acc[4][2] = {};
  gemm_core_async<64>(A, B, As, Bs, acc, K, m0, n0, kbeg, kbeg + Ksplit);

  const int lane15 = threadIdx.x & 15;
  const int quad   = (threadIdx.x & 63) >> 4;
  const int wave   = threadIdx.x >> 6;
  const int wn     = wave << 5;
  float* Cz = Cp + (size_t)blockIdx.z * 4096 * N;
#pragma unroll
  for (int fm = 0; fm < 4; ++fm)
#pragma unroll
    for (int fn = 0; fn < 2; ++fn) {
      const int col = n0 + wn + fn * 16 + lane15;
#pragma unroll
      for (int r = 0; r < 4; ++r) {
        const int row = m0 + fm * 16 + quad * 4 + r;
        Cz[(size_t)row * N + col] = acc[fm][fn][r];
      }
    }
}

// ---------------------------------------------------------------------------
// Flash attention, split-K x4. R4: LDS-traffic-per-row optimization.
// Evidence (R0-R3): runtime tracks LDS instruction count, not occupancy.
// K/V-fragment reads (16 b128/wave/tile) are fixed cost amortized over
// Q-rows/wave: 15.8 LDS-cyc/row @16 rows (R3), 9.8 @32 (R0), 6.8 @64 (R4).
// -> 4 waves x 64 q-rows/wave, 256-row Q-tile, grid 512 (2 blocks/CU).
// Latency covered by double-buffered K/V: tile t+1 issued at top of
// compute(t), end-of-iter barrier drains loads that had a full compute
// phase (~2000 cyc) in flight. LDS 69.6 KB -> exactly 2 blocks/CU.
// ---------------------------------------------------------------------------
__global__ __launch_bounds__(256, 2) void k_attn(
    const bf16* __restrict__ Q, const bf16* __restrict__ Km,
    const bf16* __restrict__ Vt, const unsigned long long* __restrict__ mb,
    bf16* __restrict__ Opart, float* __restrict__ Lpart)
{
  constexpr int PP = 72;                       // P pitch (elements)
  __shared__ __align__(16) bf16 Ks[2][64 * 64];
  __shared__ __align__(16) bf16 Vs[2][64 * 64];
  __shared__ __align__(16) bf16 Plb[4][64 * PP];

  const int tid    = threadIdx.x;
  const int wave   = tid >> 6;
  const int lane   = tid & 63;
  const int lane15 = lane & 15;
  const int quad   = lane >> 4;
  const int sp     = blockIdx.x & 3;
  const int hd     = (blockIdx.x >> 2) & 7;
  const int qt     = blockIdx.x >> 5;          // 0..15
  const int qrow   = qt * 256 + wave * 64;     // 64 rows per wave

  bf16x8 qf[4][2];
#pragma unroll
  for (int mt = 0; mt < 4; ++mt)
#pragma unroll
    for (int c = 0; c < 2; ++c)
      qf[mt][c] = *(const bf16x8*)&Q[(size_t)(qrow + mt * 16 + lane15) * 512 +
                                     hd * 64 + c * 32 + quad * 8];

  // staging: 8 K-chunks + 8 V-chunks of 1KB per tile; 2+2 per wave
  int srK[2], soK[2];
#pragma unroll
  for (int i = 0; i < 2; ++i) {
    int c  = ((wave * 2 + i) << 6) + lane;
    srK[i] = c >> 3;
    soK[i] = ((c & 7) ^ swz(srK[i])) * 8;
  }
  const bf16* KmB[2] = {
      Km + (size_t)srK[0] * 512 + hd * 64 + soK[0],
      Km + (size_t)srK[1] * 512 + hd * 64 + soK[1]};
  const bf16* VtB[2] = {
      Vt + (size_t)(hd * 64 + srK[0]) * 4096 + soK[0],
      Vt + (size_t)(hd * 64 + srK[1]) * 4096 + soK[1]};

  bf16x8 ones;
#pragma unroll
  for (int j = 0; j < 8; ++j) ones[j] = (bf16)1.0f;

  f32x4 o[4][4] = {};
  f32x4 la[4]   = {};

  const int kt0 = sp * 16;

  // prologue: stage tile kt0 into buffer 0 (one exposed drain per block)
#pragma unroll
  for (int i = 0; i < 2; ++i) {
    ASYNC_CP16(KmB[i] + (size_t)(kt0 * 64) * 512, &Ks[0][(wave * 2 + i) * 512]);
    ASYNC_CP16(VtB[i] + kt0 * 64,                 &Vs[0][(wave * 2 + i) * 512]);
  }
  __syncthreads();

  for (int kt = kt0; kt < kt0 + 16; ++kt) {
    const int cur = (kt - kt0) & 1;

    // issue tile t+1 into other buffer; in flight during entire compute(t)
    if (kt + 1 < kt0 + 16) {
      const int kb2 = (kt + 1) * 64;
#pragma unroll
      for (int i = 0; i < 2; ++i) {
        ASYNC_CP16(KmB[i] + (size_t)kb2 * 512, &Ks[cur ^ 1][(wave * 2 + i) * 512]);
        ASYNC_CP16(VtB[i] + kb2,               &Vs[cur ^ 1][(wave * 2 + i) * 512]);
      }
    }

    unsigned long long mwc[4][4];
#pragma unroll
    for (int mt = 0; mt < 4; ++mt)
#pragma unroll
      for (int r = 0; r < 4; ++r)
        mwc[mt][r] = mb[(size_t)(qrow + mt * 16 + quad * 4 + r) * 64 + kt] >> lane15;

#pragma unroll
    for (int g = 0; g < 4; ++g) {
      const int row = g * 16 + lane15;
      bf16x8 k0f = *(const bf16x8*)&Ks[cur][row * 64 + ((quad       ^ swz(row)) * 8)];
      bf16x8 k1f = *(const bf16x8*)&Ks[cur][row * 64 + (((4 + quad) ^ swz(row)) * 8)];
#pragma unroll
      for (int mt = 0; mt < 4; ++mt) {
        f32x4 s = {};
        __builtin_amdgcn_s_setprio(1);
        s = __builtin_amdgcn_mfma_f32_16x16x32_bf16(qf[mt][0], k0f, s, 0, 0, 0);
        s = __builtin_amdgcn_mfma_f32_16x16x32_bf16(qf[mt][1], k1f, s, 0, 0, 0);
        __builtin_amdgcn_s_setprio(0);
#pragma unroll
        for (int r = 0; r < 4; ++r) {
          const bool ok = ((mwc[mt][r] >> (g * 16)) & 1ull) != 0;
          // exp(s/8) = exp2(s * 0.125*log2e)
          const float p = ok ? __builtin_amdgcn_exp2f(s[r] * 0.18033688f) : 0.0f;
          Plb[wave][(mt * 16 + quad * 4 + r) * PP + g * 16 + lane15] = (bf16)p;
        }
      }
    }
    // Plb is wave-private; in-wave ds write->read ordering suffices

#pragma unroll
    for (int c2 = 0; c2 < 2; ++c2) {
      bf16x8 vf[4];
#pragma unroll
      for (int g2 = 0; g2 < 4; ++g2) {
        const int row = g2 * 16 + lane15;
        vf[g2] = *(const bf16x8*)&Vs[cur][row * 64 + (((c2 * 4 + quad) ^ swz(row)) * 8)];
      }
#pragma unroll
      for (int mt = 0; mt < 4; ++mt) {
        bf16x8 pa = *(const bf16x8*)&Plb[wave][(mt * 16 + lane15) * PP + c2 * 32 + quad * 8];
        __builtin_amdgcn_s_setprio(1);
        la[mt] = __builtin_amdgcn_mfma_f32_16x16x32_bf16(pa, ones, la[mt], 0, 0, 0);
#pragma unroll
        for (int g2 = 0; g2 < 4; ++g2)
          o[mt][g2] = __builtin_amdgcn_mfma_f32_16x16x32_bf16(pa, vf[g2], o[mt][g2], 0, 0, 0);
        __builtin_amdgcn_s_setprio(0);
      }
    }
    __syncthreads();   // drains tile t+1 loads (hidden under compute t)
  }

  bf16* Oz = Opart + (size_t)sp * 4096 * 512;
#pragma unroll
  for (int mt = 0; mt < 4; ++mt) {
#pragma unroll
    for (int g2 = 0; g2 < 4; ++g2)
#pragma unroll
      for (int r = 0; r < 4; ++r) {
        const int row = qrow + mt * 16 + quad * 4 + r;
        Oz[(size_t)row * 512 + hd * 64 + g2 * 16 + lane15] = (bf16)o[mt][g2][r];
      }
    if (lane15 == 0) {
#pragma unroll
      for (int r = 0; r < 4; ++r)
        Lpart[sp * 32768 + (qrow + mt * 16 + quad * 4 + r) * 8 + hd] = la[mt][r];
    }
  }
}

// Combine attention partials: ctx = (sum_s O_s) / (sum_s l_s).
__global__ __launch_bounds__(256) void k_attn_combine(
    const bf16* __restrict__ Opart, const float* __restrict__ Lpart,
    bf16* __restrict__ ctx)
{
  const int g = blockIdx.x * 256 + threadIdx.x;
  const size_t base = (size_t)g * 8;
  const int row = g >> 6;
  const int hd  = (g & 63) >> 3;
  float acc[8] = {};
  float l = 0.0f;
#pragma unroll
  for (int s = 0; s < 4; ++s) {
    bf16x8 ov = *(const bf16x8*)&Opart[(size_t)s * 4096 * 512 + base];
#pragma unroll
    for (int j = 0; j < 8; ++j) acc[j] += (float)ov[j];
    l += Lpart[s * 32768 + row * 8 + hd];
  }
  const float rl = 1.0f / l;
  bf16x8 y;
#pragma unroll
  for (int j = 0; j < 8; ++j) y[j] = (bf16)(acc[j] * rl);
  *(bf16x8*)(ctx + base) = y;
}

// ---------------------------------------------------------------------------
// Fused: split-K combine + bias + residual + LayerNorm. N=512 fixed.
// ---------------------------------------------------------------------------
template <int F32OUT>
__global__ __launch_bounds__(256) void k_addln_sk(
    const bf16* __restrict__ x, const float* __restrict__ Cp,
    const float* __restrict__ bias,
    const float* __restrict__ gam, const float* __restrict__ bet,
    void* __restrict__ out)
{
  const int wave = threadIdx.x >> 6, lane = threadIdx.x & 63;
  const int row  = blockIdx.x * 4 + wave;
  const size_t base = (size_t)row * 512 + lane * 8;
  const int col = lane * 8;
  bf16x8 xv = *(const bf16x8*)(x + base);
  const float* p0 = Cp + base;
  const float* p1 = Cp + (size_t)4096 * 512 + base;
  f32x4 a0 = *(const f32x4*)p0, a1 = *(const f32x4*)(p0 + 4);
  f32x4 b0 = *(const f32x4*)p1, b1 = *(const f32x4*)(p1 + 4);
  f32x4 c0 = *(const f32x4*)(bias + col), c1 = *(const f32x4*)(bias + col + 4);
  float v[8], s = 0.0f, s2 = 0.0f;
#pragma unroll
  for (int j = 0; j < 4; ++j) {
    v[j]     = (float)xv[j]     + a0[j] + b0[j] + c0[j];
    v[4 + j] = (float)xv[4 + j] + a1[j] + b1[j] + c1[j];
  }
#pragma unroll
  for (int j = 0; j < 8; ++j) { s += v[j]; s2 += v[j] * v[j]; }
#pragma unroll
  for (int d = 1; d < 64; d <<= 1) { s += __shfl_xor(s, d, 64); s2 += __shfl_xor(s2, d, 64); }
  const float mu  = s * (1.0f / 512.0f);
  const float var = s2 * (1.0f / 512.0f) - mu * mu;
  const float rs  = rsqrtf(var + 1e-5f);
  f32x4 g0 = *(const f32x4*)(gam + col), g1 = *(const f32x4*)(gam + col + 4);
  f32x4 e0 = *(const f32x4*)(bet + col), e1 = *(const f32x4*)(bet + col + 4);
  if (F32OUT) {
    float* o = (float*)out + base;
#pragma unroll
    for (int j = 0; j < 4; ++j) {
      o[j]     = ((v[j] - mu) * rs) * g0[j] + e0[j];
      o[4 + j] = ((v[4 + j] - mu) * rs) * g1[j] + e1[j];
    }
  } else {
    bf16x8 ov;
#pragma unroll
    for (int j = 0; j < 4; ++j) {
      ov[j]     = (bf16)(((v[j] - mu) * rs) * g0[j] + e0[j]);
      ov[4 + j] = (bf16)(((v[4 + j] - mu) * rs) * g1[j] + e1[j]);
    }
    *(bf16x8*)((bf16*)out + base) = ov;
  }
}

// ---------------------------------------------------------------------------
extern "C" void kernel_launch(void* const* d_in, const int* in_sizes, int n_in,
                              void* d_out, int out_size, void* d_ws, size_t ws_size,
                              hipStream_t stream)
{
  const int*   adj = (const int*)  d_in[1];
  const float* bq  = (const float*)d_in[3];
  const float* bk  = (const float*)d_in[5];
  const float* bv  = (const float*)d_in[7];
  const float* bo  = (const float*)d_in[9];
  const float* b1  = (const float*)d_in[11];
  const float* b2  = (const float*)d_in[13];
  const float* g1  = (const float*)d_in[14];
  const float* be1 = (const float*)d_in[15];
  const float* g2  = (const float*)d_in[16];
  const float* be2 = (const float*)d_in[17];

  char* ws = (char*)d_ws;
  const size_t MB = 1024 * 1024;

  // bf16 arena. Wq/Wk/Wv are contiguous, forming the concat [1536,512] matrix.
  bf16* hb  = (bf16*)(ws + 0 * MB);                  // 4 MB
  bf16* Wqb = (bf16*)(ws + 4 * MB);                  // concat base
  bf16* Wkb = (bf16*)(ws + 4 * MB + 512 * 1024);
  bf16* Wvb = (bf16*)(ws + 5 * MB);
  bf16* Wob = (bf16*)(ws + 5 * MB + 512 * 1024);
  bf16* W1b = (bf16*)(ws + 6 * MB);                  // 2 MB
  bf16* W2b = (bf16*)(ws + 8 * MB);                  // 2 MB

  // intermediates (lifetime-packed)
  bf16* q    = (bf16*)(ws + 12 * MB);   // dead after attn
  bf16* k    = (bf16*)(ws + 16 * MB);   // dead after attn
  bf16* vt   = (bf16*)(ws + 24 * MB);   // dead after attn
  unsigned long long* mbits = (unsigned long long*)(ws + 28 * MB); // 2 MB
  bf16* ctx  = (bf16*)(ws + 30 * MB);   // dead after Wo sk-gemm
  bf16*  Opart = (bf16*)(ws + 34 * MB); // 16 MB, dead after attn_combine
  float* Lpart = (float*)(ws + 50 * MB);// 0.5 MB
  float* skP   = (float*)(ws + 34 * MB);// 16 MB f32 partials (over Opart)
  bf16* h1   = (bf16*)(ws + 12 * MB);   // over q (dead)
  bf16* ff1  = (bf16*)(ws + 16 * MB);   // 16 MB over k,vt,mbits,ctx (all dead)

  // cast args
  CastArgs ca;
  const int srcIdx[7] = {0, 2, 4, 6, 8, 10, 12};
  bf16* dsts[7] = {hb, Wqb, Wkb, Wvb, Wob, W1b, W2b};
  int cum = 0;
  for (int t = 0; t < 7; ++t) {
    ca.src[t] = (const float*)d_in[srcIdx[t]];
    ca.dst[t] = dsts[t];
    ca.cum[t] = cum;
    cum += in_sizes[srcIdx[t]] / 8;
  }
  ca.cum[7] = cum;

  const dim3 blk(256);

  // 1. prep: packmask (65536 blocks) + cast
  k_prep<<<dim3(65536 + (cum + 255) / 256), blk, 0, stream>>>(adj, mbits, ca, cum);
  // 2. fused QKV (768 blocks); V blocks write vt directly
  k_gemm_qkv<<<dim3(64, 12), blk, 0, stream>>>(hb, Wqb, bq, bk, bv, q, k, vt);
  // 3. flash attention, split-K x4 (512 blocks, 256-row Q-tiles) + combine
  k_attn<<<dim3(512), blk, 0, stream>>>(q, k, vt, mbits, Opart, Lpart);
  k_attn_combine<<<dim3(1024), blk, 0, stream>>>(Opart, Lpart, ctx);
  // 4. output projection split-K x2 (512 blocks) -> fused combine+LN1 -> h1
  k_gemm_sk<<<dim3(64, 4, 2), blk, 0, stream>>>(ctx, Wob, skP, 512, 512, 256);
  k_addln_sk<0><<<dim3(1024), blk, 0, stream>>>(hb, skP, bo, g1, be1, (void*)h1);
  // 5. ff1 = relu(h1 @ W1^T + b1)  (512 blocks)
  k_gemm<<<dim3(32, 16), blk, 0, stream>>>(h1, W1b, b1, ff1, 2048, 512, 1);
  // 6. ff2 split-K x2 (512 blocks) -> fused combine+LN2 -> d_out (fp32)
  k_gemm_sk<<<dim3(64, 4, 2), blk, 0, stream>>>(ff1, W2b, skP, 512, 2048, 1024);
  k_addln_sk<1><<<dim3(1024), blk, 0, stream>>>(h1, skP, b2, g2, be2, d_out);
}

// Round 5
// 285.941 us; speedup vs baseline: 1.0741x; 1.0342x over previous
//
#include <hip/hip_runtime.h>
#include <stdint.h>
#include <stddef.h>

typedef __bf16 bf16;
typedef __bf16 bf16x8 __attribute__((ext_vector_type(8)));
typedef float  f32x4  __attribute__((ext_vector_type(4)));

typedef __attribute__((address_space(3))) void       lds_void;
typedef __attribute__((address_space(1))) const void gbl_cvoid;

#define ASYNC_CP16(g, l) \
  __builtin_amdgcn_global_load_lds((gbl_cvoid*)(g), (lds_void*)(l), 16, 0, 0)

// chunk swizzle: spreads b128 fragment reads across banks (verified round 5)
__device__ __forceinline__ int swz(int r) { return (r & 7) ^ ((r & 8) >> 1); }

// softmax scale folded into Q: exp(s/8) = exp2(s * 0.125*log2e)
#define QSCALE 0.18033688f

// ---------------------------------------------------------------------------
// Prep kernel: blocks [0,65536) pack adjacency(+I) into 64-bit masks;
// blocks [65536, ...) do the batched fp32->bf16 cast.
// ---------------------------------------------------------------------------
struct CastArgs {
  const float* src[7];
  bf16*        dst[7];
  int          cum[8];
};

__global__ __launch_bounds__(256) void k_prep(
    const int* __restrict__ adj, unsigned long long* __restrict__ mb,
    CastArgs a, int total8)
{
  const int bid = blockIdx.x;
  if (bid < 65536) {
    const int gw   = (int)(((unsigned)bid * 256 + threadIdx.x) >> 6);
    const int lane = threadIdx.x & 63;
    const int av   = adj[(size_t)gw * 64 + lane];
    unsigned long long m = __ballot(av != 0);
    const int row = gw >> 6, wc = gw & 63;
    if ((row >> 6) == wc) m |= 1ull << (row & 63);
    if (lane == 0) mb[gw] = m;
  } else {
    const int g = (bid - 65536) * 256 + threadIdx.x;
    if (g >= total8) return;
    int t = 0;
    while (a.cum[t + 1] <= g) ++t;
    const int i = g - a.cum[t];
    const float4* s = (const float4*)(a.src[t]) + (size_t)i * 2;
    const float4 x0 = s[0], x1 = s[1];
    bf16x8 y;
    y[0] = (bf16)x0.x; y[1] = (bf16)x0.y; y[2] = (bf16)x0.z; y[3] = (bf16)x0.w;
    y[4] = (bf16)x1.x; y[5] = (bf16)x1.y; y[6] = (bf16)x1.z; y[7] = (bf16)x1.w;
    *(bf16x8*)(a.dst[t] + (size_t)i * 8) = y;
  }
}

// ---------------------------------------------------------------------------
// Async-staged GEMM core, templated on m-tile (MT=128: 2x2 waves, 4x4 frags;
// MT=64: 1x4 waves, 4x2 frags). N-tile fixed 128, BK=64.
// ---------------------------------------------------------------------------
template <int MT>
__device__ __forceinline__ void gemm_core_async(
    const bf16* __restrict__ A, const bf16* __restrict__ B,
    bf16* As, bf16* Bs, f32x4 (&acc)[4][(MT == 128) ? 4 : 2],
    int K, int m0, int n0, int kbeg, int kend)
{
  constexpr int FN = (MT == 128) ? 4 : 2;
  constexpr int IA = MT / 32;             // A staging wave-instrs per wave
  const int tid    = threadIdx.x;
  const int lane   = tid & 63;
  const int wave   = tid >> 6;
  const int lane15 = lane & 15;
  const int quad   = lane >> 4;
  const int wm     = (MT == 128) ? ((wave & 1) << 6) : 0;
  const int wn     = (MT == 128) ? ((wave >> 1) << 6) : (wave << 5);

  int srA[IA], soA[IA], srB[4], soB[4];
#pragma unroll
  for (int i = 0; i < IA; ++i) {
    int c  = ((wave * IA + i) << 6) + lane;
    srA[i] = c >> 3;
    soA[i] = ((c & 7) ^ swz(srA[i])) * 8;
  }
#pragma unroll
  for (int i = 0; i < 4; ++i) {
    int c  = ((wave * 4 + i) << 6) + lane;
    srB[i] = c >> 3;
    soB[i] = ((c & 7) ^ swz(srB[i])) * 8;
  }

  const bf16* Ab = A + (size_t)m0 * K;
  const bf16* Bb = B + (size_t)n0 * K;

  for (int k0 = kbeg; k0 < kend; k0 += 64) {
#pragma unroll
    for (int i = 0; i < IA; ++i)
      ASYNC_CP16(Ab + (size_t)srA[i] * K + k0 + soA[i], &As[(wave * IA + i) * 512]);
#pragma unroll
    for (int i = 0; i < 4; ++i)
      ASYNC_CP16(Bb + (size_t)srB[i] * K + k0 + soB[i], &Bs[(wave * 4 + i) * 512]);
    __syncthreads();

#pragma unroll
    for (int kk = 0; kk < 2; ++kk) {
      bf16x8 af[4], bfr[FN];
#pragma unroll
      for (int f = 0; f < 4; ++f) {
        const int ra = wm + f * 16 + lane15;
        af[f] = *(const bf16x8*)&As[ra * 64 + (((kk * 4 + quad) ^ swz(ra)) * 8)];
      }
#pragma unroll
      for (int f = 0; f < FN; ++f) {
        const int rb = wn + f * 16 + lane15;
        bfr[f] = *(const bf16x8*)&Bs[rb * 64 + (((kk * 4 + quad) ^ swz(rb)) * 8)];
      }
#pragma unroll
      for (int fm = 0; fm < 4; ++fm)
#pragma unroll
        for (int fn = 0; fn < FN; ++fn)
          acc[fm][fn] = __builtin_amdgcn_mfma_f32_16x16x32_bf16(
              af[fm], bfr[fn], acc[fm][fn], 0, 0, 0);
    }
    __syncthreads();
  }
}

// FF1: MT=128 full-K GEMM + bias + relu.
__global__ __launch_bounds__(256, 2) void k_gemm(
    const bf16* __restrict__ A, const bf16* __restrict__ B,
    const float* __restrict__ bias, bf16* __restrict__ C,
    int N, int K, int relu)
{
  __shared__ __align__(16) bf16 As[128 * 64];
  __shared__ __align__(16) bf16 Bs[128 * 64];
  const int m0 = blockIdx.x * 128, n0 = blockIdx.y * 128;
  f32x4 acc[4][4] = {};
  gemm_core_async<128>(A, B, As, Bs, acc, K, m0, n0, 0, K);

  const int lane15 = threadIdx.x & 15;
  const int quad   = (threadIdx.x & 63) >> 4;
  const int wave   = threadIdx.x >> 6;
  const int wm = (wave & 1) << 6, wn = (wave >> 1) << 6;
#pragma unroll
  for (int fm = 0; fm < 4; ++fm)
#pragma unroll
    for (int fn = 0; fn < 4; ++fn) {
      const int col = n0 + wn + fn * 16 + lane15;
      const float bv = bias[col];
#pragma unroll
      for (int r = 0; r < 4; ++r) {
        const int row = m0 + wm + fm * 16 + quad * 4 + r;
        float v = acc[fm][fn][r] + bv;
        if (relu) v = fmaxf(v, 0.0f);
        C[(size_t)row * N + col] = (bf16)v;
      }
    }
}

// QKV: one GEMM over concat weights [1536,512] (rows 0-511 Wq, 512-1023 Wk,
// 1024-1535 Wv). MT=64 -> grid (64,12) = 768 blocks. V-projection blocks
// write vt (transposed) via an LDS transpose in the epilogue.
// Q output pre-scaled by QSCALE so attn's softmax needs no per-score mul.
__global__ __launch_bounds__(256, 4) void k_gemm_qkv(
    const bf16* __restrict__ h, const bf16* __restrict__ Wcat,
    const float* __restrict__ bq, const float* __restrict__ bk,
    const float* __restrict__ bv,
    bf16* __restrict__ q, bf16* __restrict__ k, bf16* __restrict__ vt)
{
  __shared__ __align__(16) bf16 SM[64 * 64 + 128 * 64];   // 24 KB
  bf16* As = SM;
  bf16* Bs = SM + 64 * 64;
  const int m0 = blockIdx.x * 64, n0 = blockIdx.y * 128;
  f32x4 acc[4][2] = {};
  gemm_core_async<64>(h, Wcat, As, Bs, acc, 512, m0, n0, 0, 512);

  const int lane15 = threadIdx.x & 15;
  const int quad   = (threadIdx.x & 63) >> 4;
  const int wave   = threadIdx.x >> 6;
  const int wn     = wave << 5;
  const int proj   = n0 >> 9;                  // 0=q 1=k 2=v
  const int ncol0  = n0 & 511;
  const float* bias = (proj == 0) ? bq : (proj == 1) ? bk : bv;

  if (proj < 2) {
    bf16* C = proj ? k : q;
    const float sc = proj ? 1.0f : QSCALE;
#pragma unroll
    for (int fm = 0; fm < 4; ++fm)
#pragma unroll
      for (int fn = 0; fn < 2; ++fn) {
        const int col = ncol0 + wn + fn * 16 + lane15;
        const float bvv = bias[col];
#pragma unroll
        for (int r = 0; r < 4; ++r) {
          const int row = m0 + fm * 16 + quad * 4 + r;
          C[(size_t)row * 512 + col] = (bf16)((acc[fm][fn][r] + bvv) * sc);
        }
      }
  } else {
    // transpose 64(tokens) x 128(vdims) through LDS -> vt[vdim][token]
    __syncthreads();   // K-loop LDS dead
#pragma unroll
    for (int fm = 0; fm < 4; ++fm)
#pragma unroll
      for (int fn = 0; fn < 2; ++fn) {
        const int colL = wn + fn * 16 + lane15;
        const float bvv = bias[ncol0 + colL];
#pragma unroll
        for (int r = 0; r < 4; ++r) {
          const int rowL = fm * 16 + quad * 4 + r;
          SM[colL * 72 + rowL] = (bf16)(acc[fm][fn][r] + bvv);
        }
      }
    __syncthreads();
#pragma unroll
    for (int i = 0; i < 4; ++i) {
      const int c = i * 256 + threadIdx.x;     // 1024 chunks
      const int colL = c >> 3, rw = (c & 7) * 8;
      *(bf16x8*)&vt[(size_t)(ncol0 + colL) * 4096 + m0 + rw] =
          *(const bf16x8*)&SM[colL * 72 + rw];
    }
  }
}

// Split-K GEMM (MT=64) -> f32 partials Cp[z][4096][N].
__global__ __launch_bounds__(256, 4) void k_gemm_sk(
    const bf16* __restrict__ A, const bf16* __restrict__ B,
    float* __restrict__ Cp, int N, int K, int Ksplit)
{
  __shared__ __align__(16) bf16 As[64 * 64];
  __shared__ __align__(16) bf16 Bs[128 * 64];
  const int m0 = blockIdx.x * 64, n0 = blockIdx.y * 128;
  const int kbeg = blockIdx.z * Ksplit;
  f32x4 acc[4][2] = {};
  gemm_core_async<64>(A, B, As, Bs, acc, K, m0, n0, kbeg, kbeg + Ksplit);

  const int lane15 = threadIdx.x & 15;
  const int quad   = (threadIdx.x & 63) >> 4;
  const int wave   = threadIdx.x >> 6;
  const int wn     = wave << 5;
  float* Cz = Cp + (size_t)blockIdx.z * 4096 * N;
#pragma unroll
  for (int fm = 0; fm < 4; ++fm)
#pragma unroll
    for (int fn = 0; fn < 2; ++fn) {
      const int col = n0 + wn + fn * 16 + lane15;
#pragma unroll
      for (int r = 0; r < 4; ++r) {
        const int row = m0 + fm * 16 + quad * 4 + r;
        Cz[(size_t)row * N + col] = acc[fm][fn][r];
      }
    }
}

// Rl[row*8+hd] = 1 / sum_s Lpart[s][row][hd]   (4096*8 entries)
__global__ __launch_bounds__(256) void k_rl(
    const float* __restrict__ Lpart, float* __restrict__ Rl)
{
  const int i = blockIdx.x * 256 + threadIdx.x;
  const float l = Lpart[i] + Lpart[32768 + i] + Lpart[65536 + i] + Lpart[98304 + i];
  Rl[i] = 1.0f / l;
}

// Wo projection split-K x2 with fused attention combine: A-tile is built
// on the fly as (sum_s Opart_s) * Rl, reg-staged into LDS (same chunk
// geometry + swizzle as the async path, so the MFMA loop is unchanged).
// Replaces k_attn_combine + ctx round trip.
__global__ __launch_bounds__(256, 4) void k_gemm_sk_ctx(
    const bf16* __restrict__ Op, const float* __restrict__ Rl,
    const bf16* __restrict__ B, float* __restrict__ Cp)
{
  __shared__ __align__(16) bf16 As[64 * 64];
  __shared__ __align__(16) bf16 Bs[128 * 64];
  const int tid    = threadIdx.x;
  const int lane   = tid & 63;
  const int wave   = tid >> 6;
  const int lane15 = lane & 15;
  const int quad   = lane >> 4;
  const int m0 = blockIdx.x * 64, n0 = blockIdx.y * 128;
  const int kbeg = blockIdx.z * 256;

  int srA[2], soA[2], srB[4], soB[4];
#pragma unroll
  for (int i = 0; i < 2; ++i) {
    int c  = ((wave * 2 + i) << 6) + lane;
    srA[i] = c >> 3;
    soA[i] = ((c & 7) ^ swz(srA[i])) * 8;
  }
#pragma unroll
  for (int i = 0; i < 4; ++i) {
    int c  = ((wave * 4 + i) << 6) + lane;
    srB[i] = c >> 3;
    soB[i] = ((c & 7) ^ swz(srB[i])) * 8;
  }
  const bf16* Bb = B + (size_t)n0 * 512;

  f32x4 acc[4][2] = {};

  for (int k0 = kbeg; k0 < kbeg + 256; k0 += 64) {
#pragma unroll
    for (int i = 0; i < 4; ++i)
      ASYNC_CP16(Bb + (size_t)srB[i] * 512 + k0 + soB[i], &Bs[(wave * 4 + i) * 512]);
    // reg-staged A: combine 4 partials, scale by 1/l, write LDS (linear dest)
#pragma unroll
    for (int i = 0; i < 2; ++i) {
      const int row = m0 + srA[i];
      const int col = k0 + soA[i];
      const float rl = Rl[row * 8 + (k0 >> 6)];   // col stays within head k0>>6
      const size_t base = (size_t)row * 512 + col;
      bf16x8 o0 = *(const bf16x8*)&Op[base];
      bf16x8 o1 = *(const bf16x8*)&Op[(size_t)1 * 4096 * 512 + base];
      bf16x8 o2 = *(const bf16x8*)&Op[(size_t)2 * 4096 * 512 + base];
      bf16x8 o3 = *(const bf16x8*)&Op[(size_t)3 * 4096 * 512 + base];
      bf16x8 y;
#pragma unroll
      for (int j = 0; j < 8; ++j)
        y[j] = (bf16)(((float)o0[j] + (float)o1[j] + (float)o2[j] + (float)o3[j]) * rl);
      *(bf16x8*)&As[(wave * 2 + i) * 512 + lane * 8] = y;
    }
    __syncthreads();

#pragma unroll
    for (int kk = 0; kk < 2; ++kk) {
      bf16x8 af[4], bfr[2];
#pragma unroll
      for (int f = 0; f < 4; ++f) {
        const int ra = f * 16 + lane15;
        af[f] = *(const bf16x8*)&As[ra * 64 + (((kk * 4 + quad) ^ swz(ra)) * 8)];
      }
#pragma unroll
      for (int f = 0; f < 2; ++f) {
        const int rb = (wave << 5) + f * 16 + lane15;
        bfr[f] = *(const bf16x8*)&Bs[rb * 64 + (((kk * 4 + quad) ^ swz(rb)) * 8)];
      }
#pragma unroll
      for (int fm = 0; fm < 4; ++fm)
#pragma unroll
        for (int fn = 0; fn < 2; ++fn)
          acc[fm][fn] = __builtin_amdgcn_mfma_f32_16x16x32_bf16(
              af[fm], bfr[fn], acc[fm][fn], 0, 0, 0);
    }
    __syncthreads();
  }

  float* Cz = Cp + (size_t)blockIdx.z * 4096 * 512;
  const int wn = wave << 5;
#pragma unroll
  for (int fm = 0; fm < 4; ++fm)
#pragma unroll
    for (int fn = 0; fn < 2; ++fn) {
      const int col = n0 + wn + fn * 16 + lane15;
#pragma unroll
      for (int r = 0; r < 4; ++r) {
        const int row = m0 + fm * 16 + quad * 4 + r;
        Cz[(size_t)row * 512 + col] = acc[fm][fn][r];
      }
    }
}

// ---------------------------------------------------------------------------
// Flash attention, split-K x4, 32 q-rows/wave (R0 structure restored after
// R1-R4 variants all regressed: phase-split (vmcnt poisoning), mask dbuf
// (spills), 8wx16r (2x K/V re-reads), 4wx64r dbuf (occupancy starvation).
// Only delta vs R0: Q arrives pre-scaled -> exp2(s) directly (saves a mul).
// ---------------------------------------------------------------------------
__global__ __launch_bounds__(256, 4) void k_attn(
    const bf16* __restrict__ Q, const bf16* __restrict__ Km,
    const bf16* __restrict__ Vt, const unsigned long long* __restrict__ mb,
    bf16* __restrict__ Opart, float* __restrict__ Lpart)
{
  __shared__ __align__(16) bf16 Ks[64 * 64];
  __shared__ __align__(16) bf16 Vs[64 * 64];
  __shared__ __align__(16) bf16 Plb[4][32 * 72];

  const int tid    = threadIdx.x;
  const int wave   = tid >> 6;
  const int lane   = tid & 63;
  const int lane15 = lane & 15;
  const int quad   = lane >> 4;
  const int sp     = blockIdx.x & 3;
  const int hd     = (blockIdx.x >> 2) & 7;
  const int qt     = blockIdx.x >> 5;
  const int qrow   = qt * 128 + wave * 32;

  bf16x8 qf[2][2];
#pragma unroll
  for (int mt = 0; mt < 2; ++mt)
#pragma unroll
    for (int c = 0; c < 2; ++c)
      qf[mt][c] = *(const bf16x8*)&Q[(size_t)(qrow + mt * 16 + lane15) * 512 +
                                     hd * 64 + c * 32 + quad * 8];

  // async staging bases (chunk geometry identical to GEMM core, 2 instrs/wave)
  int srK[2], soK[2];
#pragma unroll
  for (int i = 0; i < 2; ++i) {
    int c  = ((wave * 2 + i) << 6) + lane;
    srK[i] = c >> 3;
    soK[i] = ((c & 7) ^ swz(srK[i])) * 8;
  }
  const bf16* KmB[2] = {
      Km + (size_t)srK[0] * 512 + hd * 64 + soK[0],
      Km + (size_t)srK[1] * 512 + hd * 64 + soK[1]};
  const bf16* VtB[2] = {
      Vt + (size_t)(hd * 64 + srK[0]) * 4096 + soK[0],
      Vt + (size_t)(hd * 64 + srK[1]) * 4096 + soK[1]};

  bf16x8 ones;
#pragma unroll
  for (int j = 0; j < 8; ++j) ones[j] = (bf16)1.0f;

  f32x4 o[2][4] = {};
  f32x4 la[2]   = {};

  for (int kt = sp * 16; kt < sp * 16 + 16; ++kt) {
    const int kb = kt * 64;
#pragma unroll
    for (int i = 0; i < 2; ++i) {
      ASYNC_CP16(KmB[i] + (size_t)kb * 512, &Ks[(wave * 2 + i) * 512]);
      ASYNC_CP16(VtB[i] + kb,               &Vs[(wave * 2 + i) * 512]);
    }
    __syncthreads();

    unsigned long long mw[2][4];
#pragma unroll
    for (int mt = 0; mt < 2; ++mt)
#pragma unroll
      for (int r = 0; r < 4; ++r)
        mw[mt][r] = mb[(size_t)(qrow + mt * 16 + quad * 4 + r) * 64 + kt] >> lane15;

#pragma unroll
    for (int g = 0; g < 4; ++g) {
      const int row = g * 16 + lane15;
      bf16x8 k0f = *(const bf16x8*)&Ks[row * 64 + ((quad       ^ swz(row)) * 8)];
      bf16x8 k1f = *(const bf16x8*)&Ks[row * 64 + (((4 + quad) ^ swz(row)) * 8)];
#pragma unroll
      for (int mt = 0; mt < 2; ++mt) {
        f32x4 s = {};
        s = __builtin_amdgcn_mfma_f32_16x16x32_bf16(qf[mt][0], k0f, s, 0, 0, 0);
        s = __builtin_amdgcn_mfma_f32_16x16x32_bf16(qf[mt][1], k1f, s, 0, 0, 0);
#pragma unroll
        for (int r = 0; r < 4; ++r) {
          const bool ok = ((mw[mt][r] >> (g * 16)) & 1ull) != 0;
          const float p = ok ? __builtin_amdgcn_exp2f(s[r]) : 0.0f;
          Plb[wave][(mt * 16 + quad * 4 + r) * 72 + g * 16 + lane15] = (bf16)p;
        }
      }
    }

#pragma unroll
    for (int c2 = 0; c2 < 2; ++c2) {
      bf16x8 vf[4];
#pragma unroll
      for (int g2 = 0; g2 < 4; ++g2) {
        const int row = g2 * 16 + lane15;
        vf[g2] = *(const bf16x8*)&Vs[row * 64 + (((c2 * 4 + quad) ^ swz(row)) * 8)];
      }
#pragma unroll
      for (int mt = 0; mt < 2; ++mt) {
        bf16x8 pa = *(const bf16x8*)&Plb[wave][(mt * 16 + lane15) * 72 + c2 * 32 + quad * 8];
        la[mt] = __builtin_amdgcn_mfma_f32_16x16x32_bf16(pa, ones, la[mt], 0, 0, 0);
#pragma unroll
        for (int g2 = 0; g2 < 4; ++g2)
          o[mt][g2] = __builtin_amdgcn_mfma_f32_16x16x32_bf16(pa, vf[g2], o[mt][g2], 0, 0, 0);
      }
    }
    __syncthreads();
  }

  bf16* Oz = Opart + (size_t)sp * 4096 * 512;
#pragma unroll
  for (int mt = 0; mt < 2; ++mt) {
#pragma unroll
    for (int g2 = 0; g2 < 4; ++g2)
#pragma unroll
      for (int r = 0; r < 4; ++r) {
        const int row = qrow + mt * 16 + quad * 4 + r;
        Oz[(size_t)row * 512 + hd * 64 + g2 * 16 + lane15] = (bf16)o[mt][g2][r];
      }
    if (lane15 == 0) {
#pragma unroll
      for (int r = 0; r < 4; ++r)
        Lpart[sp * 32768 + (qrow + mt * 16 + quad * 4 + r) * 8 + hd] = la[mt][r];
    }
  }
}

// ---------------------------------------------------------------------------
// Fused: split-K combine + bias + residual + LayerNorm. N=512 fixed.
// ---------------------------------------------------------------------------
template <int F32OUT>
__global__ __launch_bounds__(256) void k_addln_sk(
    const bf16* __restrict__ x, const float* __restrict__ Cp,
    const float* __restrict__ bias,
    const float* __restrict__ gam, const float* __restrict__ bet,
    void* __restrict__ out)
{
  const int wave = threadIdx.x >> 6, lane = threadIdx.x & 63;
  const int row  = blockIdx.x * 4 + wave;
  const size_t base = (size_t)row * 512 + lane * 8;
  const int col = lane * 8;
  bf16x8 xv = *(const bf16x8*)(x + base);
  const float* p0 = Cp + base;
  const float* p1 = Cp + (size_t)4096 * 512 + base;
  f32x4 a0 = *(const f32x4*)p0, a1 = *(const f32x4*)(p0 + 4);
  f32x4 b0 = *(const f32x4*)p1, b1 = *(const f32x4*)(p1 + 4);
  f32x4 c0 = *(const f32x4*)(bias + col), c1 = *(const f32x4*)(bias + col + 4);
  float v[8], s = 0.0f, s2 = 0.0f;
#pragma unroll
  for (int j = 0; j < 4; ++j) {
    v[j]     = (float)xv[j]     + a0[j] + b0[j] + c0[j];
    v[4 + j] = (float)xv[4 + j] + a1[j] + b1[j] + c1[j];
  }
#pragma unroll
  for (int j = 0; j < 8; ++j) { s += v[j]; s2 += v[j] * v[j]; }
#pragma unroll
  for (int d = 1; d < 64; d <<= 1) { s += __shfl_xor(s, d, 64); s2 += __shfl_xor(s2, d, 64); }
  const float mu  = s * (1.0f / 512.0f);
  const float var = s2 * (1.0f / 512.0f) - mu * mu;
  const float rs  = rsqrtf(var + 1e-5f);
  f32x4 g0 = *(const f32x4*)(gam + col), g1 = *(const f32x4*)(gam + col + 4);
  f32x4 e0 = *(const f32x4*)(bet + col), e1 = *(const f32x4*)(bet + col + 4);
  if (F32OUT) {
    float* o = (float*)out + base;
#pragma unroll
    for (int j = 0; j < 4; ++j) {
      o[j]     = ((v[j] - mu) * rs) * g0[j] + e0[j];
      o[4 + j] = ((v[4 + j] - mu) * rs) * g1[j] + e1[j];
    }
  } else {
    bf16x8 ov;
#pragma unroll
    for (int j = 0; j < 4; ++j) {
      ov[j]     = (bf16)(((v[j] - mu) * rs) * g0[j] + e0[j]);
      ov[4 + j] = (bf16)(((v[4 + j] - mu) * rs) * g1[j] + e1[j]);
    }
    *(bf16x8*)((bf16*)out + base) = ov;
  }
}

// ---------------------------------------------------------------------------
extern "C" void kernel_launch(void* const* d_in, const int* in_sizes, int n_in,
                              void* d_out, int out_size, void* d_ws, size_t ws_size,
                              hipStream_t stream)
{
  const int*   adj = (const int*)  d_in[1];
  const float* bq  = (const float*)d_in[3];
  const float* bk  = (const float*)d_in[5];
  const float* bv  = (const float*)d_in[7];
  const float* bo  = (const float*)d_in[9];
  const float* b1  = (const float*)d_in[11];
  const float* b2  = (const float*)d_in[13];
  const float* g1  = (const float*)d_in[14];
  const float* be1 = (const float*)d_in[15];
  const float* g2  = (const float*)d_in[16];
  const float* be2 = (const float*)d_in[17];

  char* ws = (char*)d_ws;
  const size_t MB = 1024 * 1024;

  // bf16 arena. Wq/Wk/Wv are contiguous, forming the concat [1536,512] matrix.
  bf16* hb  = (bf16*)(ws + 0 * MB);                  // 4 MB
  bf16* Wqb = (bf16*)(ws + 4 * MB);                  // concat base
  bf16* Wkb = (bf16*)(ws + 4 * MB + 512 * 1024);
  bf16* Wvb = (bf16*)(ws + 5 * MB);
  bf16* Wob = (bf16*)(ws + 5 * MB + 512 * 1024);
  bf16* W1b = (bf16*)(ws + 6 * MB);                  // 2 MB
  bf16* W2b = (bf16*)(ws + 8 * MB);                  // 2 MB

  // intermediates (lifetime-packed; see per-stage notes)
  bf16* q    = (bf16*)(ws + 12 * MB);   // dead after attn
  bf16* k    = (bf16*)(ws + 16 * MB);   // dead after attn
  bf16* vt   = (bf16*)(ws + 24 * MB);   // dead after attn
  unsigned long long* mbits = (unsigned long long*)(ws + 28 * MB); // 2 MB
  bf16*  Opart = (bf16*)(ws + 34 * MB); // 16 MB, dead after Wo sk-gemm
  float* Lpart = (float*)(ws + 50 * MB);            // 0.5 MB
  float* Rl    = (float*)(ws + 50 * MB + 512 * 1024); // 128 KB
  float* skP   = (float*)(ws + 12 * MB);// 16 MB f32 partials over q,k,vt (dead)
  bf16* h1   = (bf16*)(ws + 30 * MB);   // 4 MB (free region)
  bf16* ff1  = (bf16*)(ws + 34 * MB);   // 16 MB over Opart (dead post Wo-gemm)

  // cast args
  CastArgs ca;
  const int srcIdx[7] = {0, 2, 4, 6, 8, 10, 12};
  bf16* dsts[7] = {hb, Wqb, Wkb, Wvb, Wob, W1b, W2b};
  int cum = 0;
  for (int t = 0; t < 7; ++t) {
    ca.src[t] = (const float*)d_in[srcIdx[t]];
    ca.dst[t] = dsts[t];
    ca.cum[t] = cum;
    cum += in_sizes[srcIdx[t]] / 8;
  }
  ca.cum[7] = cum;

  const dim3 blk(256);

  // 1. prep: packmask (65536 blocks) + cast
  k_prep<<<dim3(65536 + (cum + 255) / 256), blk, 0, stream>>>(adj, mbits, ca, cum);
  // 2. fused QKV (768 blocks); V blocks write vt directly; Q pre-scaled
  k_gemm_qkv<<<dim3(64, 12), blk, 0, stream>>>(hb, Wqb, bq, bk, bv, q, k, vt);
  // 3. flash attention, split-K x4 (1024 blocks)
  k_attn<<<dim3(1024), blk, 0, stream>>>(q, k, vt, mbits, Opart, Lpart);
  // 4. combine denominators, then Wo projection with fused O-combine
  k_rl<<<dim3(128), blk, 0, stream>>>(Lpart, Rl);
  k_gemm_sk_ctx<<<dim3(64, 4, 2), blk, 0, stream>>>(Opart, Rl, Wob, skP);
  k_addln_sk<0><<<dim3(1024), blk, 0, stream>>>(hb, skP, bo, g1, be1, (void*)h1);
  // 5. ff1 = relu(h1 @ W1^T + b1)  (512 blocks)
  k_gemm<<<dim3(32, 16), blk, 0, stream>>>(h1, W1b, b1, ff1, 2048, 512, 1);
  // 6. ff2 split-K x2 (512 blocks) -> fused combine+LN2 -> d_out (fp32)
  k_gemm_sk<<<dim3(64, 4, 2), blk, 0, stream>>>(ff1, W2b, skP, 512, 2048, 1024);
  k_addln_sk<1><<<dim3(1024), blk, 0, stream>>>(h1, skP, b2, g2, be2, d_out);
}

// Round 6
// 262.516 us; speedup vs baseline: 1.1699x; 1.0892x over previous
//
#include <hip/hip_runtime.h>
#include <stdint.h>
#include <stddef.h>

typedef __bf16 bf16;
typedef __bf16 bf16x8 __attribute__((ext_vector_type(8)));
typedef float  f32x4  __attribute__((ext_vector_type(4)));

typedef __attribute__((address_space(3))) void       lds_void;
typedef __attribute__((address_space(1))) const void gbl_cvoid;

#define ASYNC_CP16(g, l) \
  __builtin_amdgcn_global_load_lds((gbl_cvoid*)(g), (lds_void*)(l), 16, 0, 0)

// chunk swizzle: spreads b128 fragment reads across banks (verified round 5)
__device__ __forceinline__ int swz(int r) { return (r & 7) ^ ((r & 8) >> 1); }

// softmax scale folded into Q: exp(s/8) = exp2(s * 0.125*log2e)
#define QSCALE 0.18033688f

// ---------------------------------------------------------------------------
// Prep kernel. R6: packmask waves handle 4 mask words each (4 coalesced
// dword loads in flight/lane, amortized block prologue) -> grid 16384+cast
// blocks instead of 65536+cast. Blocks [16384,...) do the fp32->bf16 cast.
// ---------------------------------------------------------------------------
struct CastArgs {
  const float* src[7];
  bf16*        dst[7];
  int          cum[8];
};

__global__ __launch_bounds__(256) void k_prep(
    const int* __restrict__ adj, unsigned long long* __restrict__ mb,
    CastArgs a, int total8)
{
  const int bid = blockIdx.x;
  if (bid < 16384) {
    const int gw   = (int)(((unsigned)bid * 256 + threadIdx.x) >> 6); // wave id
    const int lane = threadIdx.x & 63;
    const int base = gw * 4;                       // 4 mask words per wave
    unsigned long long m[4];
#pragma unroll
    for (int j = 0; j < 4; ++j) {
      const int w  = base + j;                     // word index [0, 262144)
      const int av = adj[(size_t)w * 64 + lane];
      m[j] = __ballot(av != 0);
      const int row = w >> 6, wc = w & 63;
      if ((row >> 6) == wc) m[j] |= 1ull << (row & 63);
    }
    if (lane == 0) {
#pragma unroll
      for (int j = 0; j < 4; ++j) mb[base + j] = m[j];
    }
  } else {
    const int g = (bid - 16384) * 256 + threadIdx.x;
    if (g >= total8) return;
    int t = 0;
    while (a.cum[t + 1] <= g) ++t;
    const int i = g - a.cum[t];
    const float4* s = (const float4*)(a.src[t]) + (size_t)i * 2;
    const float4 x0 = s[0], x1 = s[1];
    bf16x8 y;
    y[0] = (bf16)x0.x; y[1] = (bf16)x0.y; y[2] = (bf16)x0.z; y[3] = (bf16)x0.w;
    y[4] = (bf16)x1.x; y[5] = (bf16)x1.y; y[6] = (bf16)x1.z; y[7] = (bf16)x1.w;
    *(bf16x8*)(a.dst[t] + (size_t)i * 8) = y;
  }
}

// ---------------------------------------------------------------------------
// Async-staged GEMM core, templated on m-tile (MT=128: 2x2 waves, 4x4 frags;
// MT=64: 1x4 waves, 4x2 frags). N-tile fixed 128, BK=64.
// ---------------------------------------------------------------------------
template <int MT>
__device__ __forceinline__ void gemm_core_async(
    const bf16* __restrict__ A, const bf16* __restrict__ B,
    bf16* As, bf16* Bs, f32x4 (&acc)[4][(MT == 128) ? 4 : 2],
    int K, int m0, int n0, int kbeg, int kend)
{
  constexpr int FN = (MT == 128) ? 4 : 2;
  constexpr int IA = MT / 32;             // A staging wave-instrs per wave
  const int tid    = threadIdx.x;
  const int lane   = tid & 63;
  const int wave   = tid >> 6;
  const int lane15 = lane & 15;
  const int quad   = lane >> 4;
  const int wm     = (MT == 128) ? ((wave & 1) << 6) : 0;
  const int wn     = (MT == 128) ? ((wave >> 1) << 6) : (wave << 5);

  int srA[IA], soA[IA], srB[4], soB[4];
#pragma unroll
  for (int i = 0; i < IA; ++i) {
    int c  = ((wave * IA + i) << 6) + lane;
    srA[i] = c >> 3;
    soA[i] = ((c & 7) ^ swz(srA[i])) * 8;
  }
#pragma unroll
  for (int i = 0; i < 4; ++i) {
    int c  = ((wave * 4 + i) << 6) + lane;
    srB[i] = c >> 3;
    soB[i] = ((c & 7) ^ swz(srB[i])) * 8;
  }

  const bf16* Ab = A + (size_t)m0 * K;
  const bf16* Bb = B + (size_t)n0 * K;

  for (int k0 = kbeg; k0 < kend; k0 += 64) {
#pragma unroll
    for (int i = 0; i < IA; ++i)
      ASYNC_CP16(Ab + (size_t)srA[i] * K + k0 + soA[i], &As[(wave * IA + i) * 512]);
#pragma unroll
    for (int i = 0; i < 4; ++i)
      ASYNC_CP16(Bb + (size_t)srB[i] * K + k0 + soB[i], &Bs[(wave * 4 + i) * 512]);
    __syncthreads();

#pragma unroll
    for (int kk = 0; kk < 2; ++kk) {
      bf16x8 af[4], bfr[FN];
#pragma unroll
      for (int f = 0; f < 4; ++f) {
        const int ra = wm + f * 16 + lane15;
        af[f] = *(const bf16x8*)&As[ra * 64 + (((kk * 4 + quad) ^ swz(ra)) * 8)];
      }
#pragma unroll
      for (int f = 0; f < FN; ++f) {
        const int rb = wn + f * 16 + lane15;
        bfr[f] = *(const bf16x8*)&Bs[rb * 64 + (((kk * 4 + quad) ^ swz(rb)) * 8)];
      }
#pragma unroll
      for (int fm = 0; fm < 4; ++fm)
#pragma unroll
        for (int fn = 0; fn < FN; ++fn)
          acc[fm][fn] = __builtin_amdgcn_mfma_f32_16x16x32_bf16(
              af[fm], bfr[fn], acc[fm][fn], 0, 0, 0);
    }
    __syncthreads();
  }
}

// FF1: MT=128 full-K GEMM + bias + relu.
__global__ __launch_bounds__(256, 2) void k_gemm(
    const bf16* __restrict__ A, const bf16* __restrict__ B,
    const float* __restrict__ bias, bf16* __restrict__ C,
    int N, int K, int relu)
{
  __shared__ __align__(16) bf16 As[128 * 64];
  __shared__ __align__(16) bf16 Bs[128 * 64];
  const int m0 = blockIdx.x * 128, n0 = blockIdx.y * 128;
  f32x4 acc[4][4] = {};
  gemm_core_async<128>(A, B, As, Bs, acc, K, m0, n0, 0, K);

  const int lane15 = threadIdx.x & 15;
  const int quad   = (threadIdx.x & 63) >> 4;
  const int wave   = threadIdx.x >> 6;
  const int wm = (wave & 1) << 6, wn = (wave >> 1) << 6;
#pragma unroll
  for (int fm = 0; fm < 4; ++fm)
#pragma unroll
    for (int fn = 0; fn < 4; ++fn) {
      const int col = n0 + wn + fn * 16 + lane15;
      const float bv = bias[col];
#pragma unroll
      for (int r = 0; r < 4; ++r) {
        const int row = m0 + wm + fm * 16 + quad * 4 + r;
        float v = acc[fm][fn][r] + bv;
        if (relu) v = fmaxf(v, 0.0f);
        C[(size_t)row * N + col] = (bf16)v;
      }
    }
}

// QKV: one GEMM over concat weights [1536,512] (rows 0-511 Wq, 512-1023 Wk,
// 1024-1535 Wv). MT=64 -> grid (64,12) = 768 blocks. V-projection blocks
// write vt (transposed) via an LDS transpose in the epilogue.
// Q output pre-scaled by QSCALE so attn's softmax needs no per-score mul.
__global__ __launch_bounds__(256, 4) void k_gemm_qkv(
    const bf16* __restrict__ h, const bf16* __restrict__ Wcat,
    const float* __restrict__ bq, const float* __restrict__ bk,
    const float* __restrict__ bv,
    bf16* __restrict__ q, bf16* __restrict__ k, bf16* __restrict__ vt)
{
  __shared__ __align__(16) bf16 SM[64 * 64 + 128 * 64];   // 24 KB
  bf16* As = SM;
  bf16* Bs = SM + 64 * 64;
  const int m0 = blockIdx.x * 64, n0 = blockIdx.y * 128;
  f32x4 acc[4][2] = {};
  gemm_core_async<64>(h, Wcat, As, Bs, acc, 512, m0, n0, 0, 512);

  const int lane15 = threadIdx.x & 15;
  const int quad   = (threadIdx.x & 63) >> 4;
  const int wave   = threadIdx.x >> 6;
  const int wn     = wave << 5;
  const int proj   = n0 >> 9;                  // 0=q 1=k 2=v
  const int ncol0  = n0 & 511;
  const float* bias = (proj == 0) ? bq : (proj == 1) ? bk : bv;

  if (proj < 2) {
    bf16* C = proj ? k : q;
    const float sc = proj ? 1.0f : QSCALE;
#pragma unroll
    for (int fm = 0; fm < 4; ++fm)
#pragma unroll
      for (int fn = 0; fn < 2; ++fn) {
        const int col = ncol0 + wn + fn * 16 + lane15;
        const float bvv = bias[col];
#pragma unroll
        for (int r = 0; r < 4; ++r) {
          const int row = m0 + fm * 16 + quad * 4 + r;
          C[(size_t)row * 512 + col] = (bf16)((acc[fm][fn][r] + bvv) * sc);
        }
      }
  } else {
    // transpose 64(tokens) x 128(vdims) through LDS -> vt[vdim][token]
    __syncthreads();   // K-loop LDS dead
#pragma unroll
    for (int fm = 0; fm < 4; ++fm)
#pragma unroll
      for (int fn = 0; fn < 2; ++fn) {
        const int colL = wn + fn * 16 + lane15;
        const float bvv = bias[ncol0 + colL];
#pragma unroll
        for (int r = 0; r < 4; ++r) {
          const int rowL = fm * 16 + quad * 4 + r;
          SM[colL * 72 + rowL] = (bf16)(acc[fm][fn][r] + bvv);
        }
      }
    __syncthreads();
#pragma unroll
    for (int i = 0; i < 4; ++i) {
      const int c = i * 256 + threadIdx.x;     // 1024 chunks
      const int colL = c >> 3, rw = (c & 7) * 8;
      *(bf16x8*)&vt[(size_t)(ncol0 + colL) * 4096 + m0 + rw] =
          *(const bf16x8*)&SM[colL * 72 + rw];
    }
  }
}

// Split-K GEMM (MT=64) -> f32 partials Cp[z][4096][N].
__global__ __launch_bounds__(256, 4) void k_gemm_sk(
    const bf16* __restrict__ A, const bf16* __restrict__ B,
    float* __restrict__ Cp, int N, int K, int Ksplit)
{
  __shared__ __align__(16) bf16 As[64 * 64];
  __shared__ __align__(16) bf16 Bs[128 * 64];
  const int m0 = blockIdx.x * 64, n0 = blockIdx.y * 128;
  const int kbeg = blockIdx.z * Ksplit;
  f32x4 acc[4][2] = {};
  gemm_core_async<64>(A, B, As, Bs, acc, K, m0, n0, kbeg, kbeg + Ksplit);

  const int lane15 = threadIdx.x & 15;
  const int quad   = (threadIdx.x & 63) >> 4;
  const int wave   = threadIdx.x >> 6;
  const int wn     = wave << 5;
  float* Cz = Cp + (size_t)blockIdx.z * 4096 * N;
#pragma unroll
  for (int fm = 0; fm < 4; ++fm)
#pragma unroll
    for (int fn = 0; fn < 2; ++fn) {
      const int col = n0 + wn + fn * 16 + lane15;
#pragma unroll
      for (int r = 0; r < 4; ++r) {
        const int row = m0 + fm * 16 + quad * 4 + r;
        Cz[(size_t)row * N + col] = acc[fm][fn][r];
      }
    }
}

// Wo projection split-K x2 with fused attention combine: A-tile is built
// on the fly as (sum_s Opart_s) * (1/sum_s l_s), reg-staged into LDS (same
// chunk geometry + swizzle as the async path). R6: the 1/l table is computed
// in-kernel (2-KB LDS, 2 entries/thread) -> k_rl launch deleted.
__global__ __launch_bounds__(256, 4) void k_gemm_sk_ctx(
    const bf16* __restrict__ Op, const float* __restrict__ Lp,
    const bf16* __restrict__ B, float* __restrict__ Cp)
{
  __shared__ __align__(16) bf16 As[64 * 64];
  __shared__ __align__(16) bf16 Bs[128 * 64];
  __shared__ float Rls[64 * 8];
  const int tid    = threadIdx.x;
  const int lane   = tid & 63;
  const int wave   = tid >> 6;
  const int lane15 = lane & 15;
  const int quad   = lane >> 4;
  const int m0 = blockIdx.x * 64, n0 = blockIdx.y * 128;
  const int kbeg = blockIdx.z * 256;

  // prologue: per-row/head reciprocal denominators (512 entries, 2/thread)
#pragma unroll
  for (int e = tid * 2; e < tid * 2 + 2; ++e) {
    const int ri = (m0 + (e >> 3)) * 8 + (e & 7);
    const float l = Lp[ri] + Lp[32768 + ri] + Lp[65536 + ri] + Lp[98304 + ri];
    Rls[e] = 1.0f / l;
  }
  __syncthreads();

  int srA[2], soA[2], srB[4], soB[4];
#pragma unroll
  for (int i = 0; i < 2; ++i) {
    int c  = ((wave * 2 + i) << 6) + lane;
    srA[i] = c >> 3;
    soA[i] = ((c & 7) ^ swz(srA[i])) * 8;
  }
#pragma unroll
  for (int i = 0; i < 4; ++i) {
    int c  = ((wave * 4 + i) << 6) + lane;
    srB[i] = c >> 3;
    soB[i] = ((c & 7) ^ swz(srB[i])) * 8;
  }
  const bf16* Bb = B + (size_t)n0 * 512;

  f32x4 acc[4][2] = {};

  for (int k0 = kbeg; k0 < kbeg + 256; k0 += 64) {
#pragma unroll
    for (int i = 0; i < 4; ++i)
      ASYNC_CP16(Bb + (size_t)srB[i] * 512 + k0 + soB[i], &Bs[(wave * 4 + i) * 512]);
    // reg-staged A: combine 4 partials, scale by 1/l, write LDS (linear dest)
#pragma unroll
    for (int i = 0; i < 2; ++i) {
      const int row = m0 + srA[i];
      const int col = k0 + soA[i];
      const float rl = Rls[srA[i] * 8 + (k0 >> 6)];   // col's head = k0>>6
      const size_t base = (size_t)row * 512 + col;
      bf16x8 o0 = *(const bf16x8*)&Op[base];
      bf16x8 o1 = *(const bf16x8*)&Op[(size_t)1 * 4096 * 512 + base];
      bf16x8 o2 = *(const bf16x8*)&Op[(size_t)2 * 4096 * 512 + base];
      bf16x8 o3 = *(const bf16x8*)&Op[(size_t)3 * 4096 * 512 + base];
      bf16x8 y;
#pragma unroll
      for (int j = 0; j < 8; ++j)
        y[j] = (bf16)(((float)o0[j] + (float)o1[j] + (float)o2[j] + (float)o3[j]) * rl);
      *(bf16x8*)&As[(wave * 2 + i) * 512 + lane * 8] = y;
    }
    __syncthreads();

#pragma unroll
    for (int kk = 0; kk < 2; ++kk) {
      bf16x8 af[4], bfr[2];
#pragma unroll
      for (int f = 0; f < 4; ++f) {
        const int ra = f * 16 + lane15;
        af[f] = *(const bf16x8*)&As[ra * 64 + (((kk * 4 + quad) ^ swz(ra)) * 8)];
      }
#pragma unroll
      for (int f = 0; f < 2; ++f) {
        const int rb = (wave << 5) + f * 16 + lane15;
        bfr[f] = *(const bf16x8*)&Bs[rb * 64 + (((kk * 4 + quad) ^ swz(rb)) * 8)];
      }
#pragma unroll
      for (int fm = 0; fm < 4; ++fm)
#pragma unroll
        for (int fn = 0; fn < 2; ++fn)
          acc[fm][fn] = __builtin_amdgcn_mfma_f32_16x16x32_bf16(
              af[fm], bfr[fn], acc[fm][fn], 0, 0, 0);
    }
    __syncthreads();
  }

  float* Cz = Cp + (size_t)blockIdx.z * 4096 * 512;
  const int wn = wave << 5;
#pragma unroll
  for (int fm = 0; fm < 4; ++fm)
#pragma unroll
    for (int fn = 0; fn < 2; ++fn) {
      const int col = n0 + wn + fn * 16 + lane15;
#pragma unroll
      for (int r = 0; r < 4; ++r) {
        const int row = m0 + fm * 16 + quad * 4 + r;
        Cz[(size_t)row * 512 + col] = acc[fm][fn][r];
      }
    }
}

// ---------------------------------------------------------------------------
// Flash attention, split-K x4, 32 q-rows/wave (R0 structure; verified local
// optimum after R1-R4 variants all regressed). Q arrives pre-scaled ->
// exp2(s) directly.
// ---------------------------------------------------------------------------
__global__ __launch_bounds__(256, 4) void k_attn(
    const bf16* __restrict__ Q, const bf16* __restrict__ Km,
    const bf16* __restrict__ Vt, const unsigned long long* __restrict__ mb,
    bf16* __restrict__ Opart, float* __restrict__ Lpart)
{
  __shared__ __align__(16) bf16 Ks[64 * 64];
  __shared__ __align__(16) bf16 Vs[64 * 64];
  __shared__ __align__(16) bf16 Plb[4][32 * 72];

  const int tid    = threadIdx.x;
  const int wave   = tid >> 6;
  const int lane   = tid & 63;
  const int lane15 = lane & 15;
  const int quad   = lane >> 4;
  const int sp     = blockIdx.x & 3;
  const int hd     = (blockIdx.x >> 2) & 7;
  const int qt     = blockIdx.x >> 5;
  const int qrow   = qt * 128 + wave * 32;

  bf16x8 qf[2][2];
#pragma unroll
  for (int mt = 0; mt < 2; ++mt)
#pragma unroll
    for (int c = 0; c < 2; ++c)
      qf[mt][c] = *(const bf16x8*)&Q[(size_t)(qrow + mt * 16 + lane15) * 512 +
                                     hd * 64 + c * 32 + quad * 8];

  // async staging bases (chunk geometry identical to GEMM core, 2 instrs/wave)
  int srK[2], soK[2];
#pragma unroll
  for (int i = 0; i < 2; ++i) {
    int c  = ((wave * 2 + i) << 6) + lane;
    srK[i] = c >> 3;
    soK[i] = ((c & 7) ^ swz(srK[i])) * 8;
  }
  const bf16* KmB[2] = {
      Km + (size_t)srK[0] * 512 + hd * 64 + soK[0],
      Km + (size_t)srK[1] * 512 + hd * 64 + soK[1]};
  const bf16* VtB[2] = {
      Vt + (size_t)(hd * 64 + srK[0]) * 4096 + soK[0],
      Vt + (size_t)(hd * 64 + srK[1]) * 4096 + soK[1]};

  bf16x8 ones;
#pragma unroll
  for (int j = 0; j < 8; ++j) ones[j] = (bf16)1.0f;

  f32x4 o[2][4] = {};
  f32x4 la[2]   = {};

  for (int kt = sp * 16; kt < sp * 16 + 16; ++kt) {
    const int kb = kt * 64;
#pragma unroll
    for (int i = 0; i < 2; ++i) {
      ASYNC_CP16(KmB[i] + (size_t)kb * 512, &Ks[(wave * 2 + i) * 512]);
      ASYNC_CP16(VtB[i] + kb,               &Vs[(wave * 2 + i) * 512]);
    }
    __syncthreads();

    unsigned long long mw[2][4];
#pragma unroll
    for (int mt = 0; mt < 2; ++mt)
#pragma unroll
      for (int r = 0; r < 4; ++r)
        mw[mt][r] = mb[(size_t)(qrow + mt * 16 + quad * 4 + r) * 64 + kt] >> lane15;

#pragma unroll
    for (int g = 0; g < 4; ++g) {
      const int row = g * 16 + lane15;
      bf16x8 k0f = *(const bf16x8*)&Ks[row * 64 + ((quad       ^ swz(row)) * 8)];
      bf16x8 k1f = *(const bf16x8*)&Ks[row * 64 + (((4 + quad) ^ swz(row)) * 8)];
#pragma unroll
      for (int mt = 0; mt < 2; ++mt) {
        f32x4 s = {};
        s = __builtin_amdgcn_mfma_f32_16x16x32_bf16(qf[mt][0], k0f, s, 0, 0, 0);
        s = __builtin_amdgcn_mfma_f32_16x16x32_bf16(qf[mt][1], k1f, s, 0, 0, 0);
#pragma unroll
        for (int r = 0; r < 4; ++r) {
          const bool ok = ((mw[mt][r] >> (g * 16)) & 1ull) != 0;
          const float p = ok ? __builtin_amdgcn_exp2f(s[r]) : 0.0f;
          Plb[wave][(mt * 16 + quad * 4 + r) * 72 + g * 16 + lane15] = (bf16)p;
        }
      }
    }

#pragma unroll
    for (int c2 = 0; c2 < 2; ++c2) {
      bf16x8 vf[4];
#pragma unroll
      for (int g2 = 0; g2 < 4; ++g2) {
        const int row = g2 * 16 + lane15;
        vf[g2] = *(const bf16x8*)&Vs[row * 64 + (((c2 * 4 + quad) ^ swz(row)) * 8)];
      }
#pragma unroll
      for (int mt = 0; mt < 2; ++mt) {
        bf16x8 pa = *(const bf16x8*)&Plb[wave][(mt * 16 + lane15) * 72 + c2 * 32 + quad * 8];
        la[mt] = __builtin_amdgcn_mfma_f32_16x16x32_bf16(pa, ones, la[mt], 0, 0, 0);
#pragma unroll
        for (int g2 = 0; g2 < 4; ++g2)
          o[mt][g2] = __builtin_amdgcn_mfma_f32_16x16x32_bf16(pa, vf[g2], o[mt][g2], 0, 0, 0);
      }
    }
    __syncthreads();
  }

  bf16* Oz = Opart + (size_t)sp * 4096 * 512;
#pragma unroll
  for (int mt = 0; mt < 2; ++mt) {
#pragma unroll
    for (int g2 = 0; g2 < 4; ++g2)
#pragma unroll
      for (int r = 0; r < 4; ++r) {
        const int row = qrow + mt * 16 + quad * 4 + r;
        Oz[(size_t)row * 512 + hd * 64 + g2 * 16 + lane15] = (bf16)o[mt][g2][r];
      }
    if (lane15 == 0) {
#pragma unroll
      for (int r = 0; r < 4; ++r)
        Lpart[sp * 32768 + (qrow + mt * 16 + quad * 4 + r) * 8 + hd] = la[mt][r];
    }
  }
}

// ---------------------------------------------------------------------------
// Fused: split-K combine + bias + residual + LayerNorm. N=512 fixed.
// ---------------------------------------------------------------------------
template <int F32OUT>
__global__ __launch_bounds__(256) void k_addln_sk(
    const bf16* __restrict__ x, const float* __restrict__ Cp,
    const float* __restrict__ bias,
    const float* __restrict__ gam, const float* __restrict__ bet,
    void* __restrict__ out)
{
  const int wave = threadIdx.x >> 6, lane = threadIdx.x & 63;
  const int row  = blockIdx.x * 4 + wave;
  const size_t base = (size_t)row * 512 + lane * 8;
  const int col = lane * 8;
  bf16x8 xv = *(const bf16x8*)(x + base);
  const float* p0 = Cp + base;
  const float* p1 = Cp + (size_t)4096 * 512 + base;
  f32x4 a0 = *(const f32x4*)p0, a1 = *(const f32x4*)(p0 + 4);
  f32x4 b0 = *(const f32x4*)p1, b1 = *(const f32x4*)(p1 + 4);
  f32x4 c0 = *(const f32x4*)(bias + col), c1 = *(const f32x4*)(bias + col + 4);
  float v[8], s = 0.0f, s2 = 0.0f;
#pragma unroll
  for (int j = 0; j < 4; ++j) {
    v[j]     = (float)xv[j]     + a0[j] + b0[j] + c0[j];
    v[4 + j] = (float)xv[4 + j] + a1[j] + b1[j] + c1[j];
  }
#pragma unroll
  for (int j = 0; j < 8; ++j) { s += v[j]; s2 += v[j] * v[j]; }
#pragma unroll
  for (int d = 1; d < 64; d <<= 1) { s += __shfl_xor(s, d, 64); s2 += __shfl_xor(s2, d, 64); }
  const float mu  = s * (1.0f / 512.0f);
  const float var = s2 * (1.0f / 512.0f) - mu * mu;
  const float rs  = rsqrtf(var + 1e-5f);
  f32x4 g0 = *(const f32x4*)(gam + col), g1 = *(const f32x4*)(gam + col + 4);
  f32x4 e0 = *(const f32x4*)(bet + col), e1 = *(const f32x4*)(bet + col + 4);
  if (F32OUT) {
    float* o = (float*)out + base;
#pragma unroll
    for (int j = 0; j < 4; ++j) {
      o[j]     = ((v[j] - mu) * rs) * g0[j] + e0[j];
      o[4 + j] = ((v[4 + j] - mu) * rs) * g1[j] + e1[j];
    }
  } else {
    bf16x8 ov;
#pragma unroll
    for (int j = 0; j < 4; ++j) {
      ov[j]     = (bf16)(((v[j] - mu) * rs) * g0[j] + e0[j]);
      ov[4 + j] = (bf16)(((v[4 + j] - mu) * rs) * g1[j] + e1[j]);
    }
    *(bf16x8*)((bf16*)out + base) = ov;
  }
}

// ---------------------------------------------------------------------------
extern "C" void kernel_launch(void* const* d_in, const int* in_sizes, int n_in,
                              void* d_out, int out_size, void* d_ws, size_t ws_size,
                              hipStream_t stream)
{
  const int*   adj = (const int*)  d_in[1];
  const float* bq  = (const float*)d_in[3];
  const float* bk  = (const float*)d_in[5];
  const float* bv  = (const float*)d_in[7];
  const float* bo  = (const float*)d_in[9];
  const float* b1  = (const float*)d_in[11];
  const float* b2  = (const float*)d_in[13];
  const float* g1  = (const float*)d_in[14];
  const float* be1 = (const float*)d_in[15];
  const float* g2  = (const float*)d_in[16];
  const float* be2 = (const float*)d_in[17];

  char* ws = (char*)d_ws;
  const size_t MB = 1024 * 1024;

  // bf16 arena. Wq/Wk/Wv are contiguous, forming the concat [1536,512] matrix.
  bf16* hb  = (bf16*)(ws + 0 * MB);                  // 4 MB
  bf16* Wqb = (bf16*)(ws + 4 * MB);                  // concat base
  bf16* Wkb = (bf16*)(ws + 4 * MB + 512 * 1024);
  bf16* Wvb = (bf16*)(ws + 5 * MB);
  bf16* Wob = (bf16*)(ws + 5 * MB + 512 * 1024);
  bf16* W1b = (bf16*)(ws + 6 * MB);                  // 2 MB
  bf16* W2b = (bf16*)(ws + 8 * MB);                  // 2 MB

  // intermediates (lifetime-packed; see per-stage notes)
  bf16* q    = (bf16*)(ws + 12 * MB);   // dead after attn
  bf16* k    = (bf16*)(ws + 16 * MB);   // dead after attn
  bf16* vt   = (bf16*)(ws + 24 * MB);   // dead after attn
  unsigned long long* mbits = (unsigned long long*)(ws + 28 * MB); // 2 MB
  bf16*  Opart = (bf16*)(ws + 34 * MB); // 16 MB, dead after Wo sk-gemm
  float* Lpart = (float*)(ws + 50 * MB);            // 0.5 MB
  float* skP   = (float*)(ws + 12 * MB);// 16 MB f32 partials over q,k,vt (dead)
  bf16* h1   = (bf16*)(ws + 30 * MB);   // 4 MB (free region)
  bf16* ff1  = (bf16*)(ws + 34 * MB);   // 16 MB over Opart (dead post Wo-gemm)

  // cast args
  CastArgs ca;
  const int srcIdx[7] = {0, 2, 4, 6, 8, 10, 12};
  bf16* dsts[7] = {hb, Wqb, Wkb, Wvb, Wob, W1b, W2b};
  int cum = 0;
  for (int t = 0; t < 7; ++t) {
    ca.src[t] = (const float*)d_in[srcIdx[t]];
    ca.dst[t] = dsts[t];
    ca.cum[t] = cum;
    cum += in_sizes[srcIdx[t]] / 8;
  }
  ca.cum[7] = cum;

  const dim3 blk(256);

  // 1. prep: packmask (16384 blocks, 4 words/wave) + cast
  k_prep<<<dim3(16384 + (cum + 255) / 256), blk, 0, stream>>>(adj, mbits, ca, cum);
  // 2. fused QKV (768 blocks); V blocks write vt directly; Q pre-scaled
  k_gemm_qkv<<<dim3(64, 12), blk, 0, stream>>>(hb, Wqb, bq, bk, bv, q, k, vt);
  // 3. flash attention, split-K x4 (1024 blocks)
  k_attn<<<dim3(1024), blk, 0, stream>>>(q, k, vt, mbits, Opart, Lpart);
  // 4. Wo projection with fused O-combine + in-kernel 1/l (k_rl deleted)
  k_gemm_sk_ctx<<<dim3(64, 4, 2), blk, 0, stream>>>(Opart, Lpart, Wob, skP);
  k_addln_sk<0><<<dim3(1024), blk, 0, stream>>>(hb, skP, bo, g1, be1, (void*)h1);
  // 5. ff1 = relu(h1 @ W1^T + b1)  (512 blocks)
  k_gemm<<<dim3(32, 16), blk, 0, stream>>>(h1, W1b, b1, ff1, 2048, 512, 1);
  // 6. ff2 split-K x2 (512 blocks) -> fused combine+LN2 -> d_out (fp32)
  k_gemm_sk<<<dim3(64, 4, 2), blk, 0, stream>>>(ff1, W2b, skP, 512, 2048, 1024);
  k_addln_sk<1><<<dim3(1024), blk, 0, stream>>>(h1, skP, b2, g2, be2, d_out);
}

// Round 8
// 259.921 us; speedup vs baseline: 1.1816x; 1.0100x over previous
//
#include <hip/hip_runtime.h>
#include <stdint.h>
#include <stddef.h>

typedef __bf16 bf16;
typedef __bf16 bf16x4 __attribute__((ext_vector_type(4)));
typedef __bf16 bf16x8 __attribute__((ext_vector_type(8)));
typedef float  f32x4  __attribute__((ext_vector_type(4)));

typedef __attribute__((address_space(3))) void       lds_void;
typedef __attribute__((address_space(1))) const void gbl_cvoid;

#define ASYNC_CP16(g, l) \
  __builtin_amdgcn_global_load_lds((gbl_cvoid*)(g), (lds_void*)(l), 16, 0, 0)

// chunk swizzle: spreads b128 fragment reads across banks (verified round 5)
__device__ __forceinline__ int swz(int r) { return (r & 7) ^ ((r & 8) >> 1); }

// softmax scale folded into Q: exp(s/8) = exp2(s * 0.125*log2e)
#define QSCALE 0.18033688f

// ---------------------------------------------------------------------------
// Prep kernel. Packmask waves handle 4 mask words each -> grid 16384+cast
// blocks. Blocks [16384,...) do the fp32->bf16 cast.
// ---------------------------------------------------------------------------
struct CastArgs {
  const float* src[7];
  bf16*        dst[7];
  int          cum[8];
};

__global__ __launch_bounds__(256) void k_prep(
    const int* __restrict__ adj, unsigned long long* __restrict__ mb,
    CastArgs a, int total8)
{
  const int bid = blockIdx.x;
  if (bid < 16384) {
    const int gw   = (int)(((unsigned)bid * 256 + threadIdx.x) >> 6); // wave id
    const int lane = threadIdx.x & 63;
    const int base = gw * 4;                       // 4 mask words per wave
    unsigned long long m[4];
#pragma unroll
    for (int j = 0; j < 4; ++j) {
      const int w  = base + j;                     // word index [0, 262144)
      const int av = adj[(size_t)w * 64 + lane];
      m[j] = __ballot(av != 0);
      const int row = w >> 6, wc = w & 63;
      if ((row >> 6) == wc) m[j] |= 1ull << (row & 63);
    }
    if (lane == 0) {
#pragma unroll
      for (int j = 0; j < 4; ++j) mb[base + j] = m[j];
    }
  } else {
    const int g = (bid - 16384) * 256 + threadIdx.x;
    if (g >= total8) return;
    int t = 0;
    while (a.cum[t + 1] <= g) ++t;
    const int i = g - a.cum[t];
    const float4* s = (const float4*)(a.src[t]) + (size_t)i * 2;
    const float4 x0 = s[0], x1 = s[1];
    bf16x8 y;
    y[0] = (bf16)x0.x; y[1] = (bf16)x0.y; y[2] = (bf16)x0.z; y[3] = (bf16)x0.w;
    y[4] = (bf16)x1.x; y[5] = (bf16)x1.y; y[6] = (bf16)x1.z; y[7] = (bf16)x1.w;
    *(bf16x8*)(a.dst[t] + (size_t)i * 8) = y;
  }
}

// ---------------------------------------------------------------------------
// Async-staged GEMM core, templated on m-tile (MT=128: 2x2 waves, 4x4 frags;
// MT=64: 1x4 waves, 4x2 frags). N-tile fixed 128, BK=64.
// ---------------------------------------------------------------------------
template <int MT>
__device__ __forceinline__ void gemm_core_async(
    const bf16* __restrict__ A, const bf16* __restrict__ B,
    bf16* As, bf16* Bs, f32x4 (&acc)[4][(MT == 128) ? 4 : 2],
    int K, int m0, int n0, int kbeg, int kend)
{
  constexpr int FN = (MT == 128) ? 4 : 2;
  constexpr int IA = MT / 32;             // A staging wave-instrs per wave
  const int tid    = threadIdx.x;
  const int lane   = tid & 63;
  const int wave   = tid >> 6;
  const int lane15 = lane & 15;
  const int quad   = lane >> 4;
  const int wm     = (MT == 128) ? ((wave & 1) << 6) : 0;
  const int wn     = (MT == 128) ? ((wave >> 1) << 6) : (wave << 5);

  int srA[IA], soA[IA], srB[4], soB[4];
#pragma unroll
  for (int i = 0; i < IA; ++i) {
    int c  = ((wave * IA + i) << 6) + lane;
    srA[i] = c >> 3;
    soA[i] = ((c & 7) ^ swz(srA[i])) * 8;
  }
#pragma unroll
  for (int i = 0; i < 4; ++i) {
    int c  = ((wave * 4 + i) << 6) + lane;
    srB[i] = c >> 3;
    soB[i] = ((c & 7) ^ swz(srB[i])) * 8;
  }

  const bf16* Ab = A + (size_t)m0 * K;
  const bf16* Bb = B + (size_t)n0 * K;

  for (int k0 = kbeg; k0 < kend; k0 += 64) {
#pragma unroll
    for (int i = 0; i < IA; ++i)
      ASYNC_CP16(Ab + (size_t)srA[i] * K + k0 + soA[i], &As[(wave * IA + i) * 512]);
#pragma unroll
    for (int i = 0; i < 4; ++i)
      ASYNC_CP16(Bb + (size_t)srB[i] * K + k0 + soB[i], &Bs[(wave * 4 + i) * 512]);
    __syncthreads();

#pragma unroll
    for (int kk = 0; kk < 2; ++kk) {
      bf16x8 af[4], bfr[FN];
#pragma unroll
      for (int f = 0; f < 4; ++f) {
        const int ra = wm + f * 16 + lane15;
        af[f] = *(const bf16x8*)&As[ra * 64 + (((kk * 4 + quad) ^ swz(ra)) * 8)];
      }
#pragma unroll
      for (int f = 0; f < FN; ++f) {
        const int rb = wn + f * 16 + lane15;
        bfr[f] = *(const bf16x8*)&Bs[rb * 64 + (((kk * 4 + quad) ^ swz(rb)) * 8)];
      }
#pragma unroll
      for (int fm = 0; fm < 4; ++fm)
#pragma unroll
        for (int fn = 0; fn < FN; ++fn)
          acc[fm][fn] = __builtin_amdgcn_mfma_f32_16x16x32_bf16(
              af[fm], bfr[fn], acc[fm][fn], 0, 0, 0);
    }
    __syncthreads();
  }
}

// FF1: MT=128 full-K GEMM + bias + relu.
__global__ __launch_bounds__(256, 2) void k_gemm(
    const bf16* __restrict__ A, const bf16* __restrict__ B,
    const float* __restrict__ bias, bf16* __restrict__ C,
    int N, int K, int relu)
{
  __shared__ __align__(16) bf16 As[128 * 64];
  __shared__ __align__(16) bf16 Bs[128 * 64];
  const int m0 = blockIdx.x * 128, n0 = blockIdx.y * 128;
  f32x4 acc[4][4] = {};
  gemm_core_async<128>(A, B, As, Bs, acc, K, m0, n0, 0, K);

  const int lane15 = threadIdx.x & 15;
  const int quad   = (threadIdx.x & 63) >> 4;
  const int wave   = threadIdx.x >> 6;
  const int wm = (wave & 1) << 6, wn = (wave >> 1) << 6;
#pragma unroll
  for (int fm = 0; fm < 4; ++fm)
#pragma unroll
    for (int fn = 0; fn < 4; ++fn) {
      const int col = n0 + wn + fn * 16 + lane15;
      const float bv = bias[col];
#pragma unroll
      for (int r = 0; r < 4; ++r) {
        const int row = m0 + wm + fm * 16 + quad * 4 + r;
        float v = acc[fm][fn][r] + bv;
        if (relu) v = fmaxf(v, 0.0f);
        C[(size_t)row * N + col] = (bf16)v;
      }
    }
}

// QKV: one GEMM over concat weights [1536,512] (rows 0-511 Wq, 512-1023 Wk,
// 1024-1535 Wv). MT=64 -> grid (64,12) = 768 blocks. V-projection blocks
// write vt (transposed) via an LDS transpose in the epilogue.
// Q output pre-scaled by QSCALE so attn's softmax needs no per-score mul.
__global__ __launch_bounds__(256, 4) void k_gemm_qkv(
    const bf16* __restrict__ h, const bf16* __restrict__ Wcat,
    const float* __restrict__ bq, const float* __restrict__ bk,
    const float* __restrict__ bv,
    bf16* __restrict__ q, bf16* __restrict__ k, bf16* __restrict__ vt)
{
  __shared__ __align__(16) bf16 SM[64 * 64 + 128 * 64];   // 24 KB
  bf16* As = SM;
  bf16* Bs = SM + 64 * 64;
  const int m0 = blockIdx.x * 64, n0 = blockIdx.y * 128;
  f32x4 acc[4][2] = {};
  gemm_core_async<64>(h, Wcat, As, Bs, acc, 512, m0, n0, 0, 512);

  const int lane15 = threadIdx.x & 15;
  const int quad   = (threadIdx.x & 63) >> 4;
  const int wave   = threadIdx.x >> 6;
  const int wn     = wave << 5;
  const int proj   = n0 >> 9;                  // 0=q 1=k 2=v
  const int ncol0  = n0 & 511;
  const float* bias = (proj == 0) ? bq : (proj == 1) ? bk : bv;

  if (proj < 2) {
    bf16* C = proj ? k : q;
    const float sc = proj ? 1.0f : QSCALE;
#pragma unroll
    for (int fm = 0; fm < 4; ++fm)
#pragma unroll
      for (int fn = 0; fn < 2; ++fn) {
        const int col = ncol0 + wn + fn * 16 + lane15;
        const float bvv = bias[col];
#pragma unroll
        for (int r = 0; r < 4; ++r) {
          const int row = m0 + fm * 16 + quad * 4 + r;
          C[(size_t)row * 512 + col] = (bf16)((acc[fm][fn][r] + bvv) * sc);
        }
      }
  } else {
    // transpose 64(tokens) x 128(vdims) through LDS -> vt[vdim][token]
    __syncthreads();   // K-loop LDS dead
#pragma unroll
    for (int fm = 0; fm < 4; ++fm)
#pragma unroll
      for (int fn = 0; fn < 2; ++fn) {
        const int colL = wn + fn * 16 + lane15;
        const float bvv = bias[ncol0 + colL];
#pragma unroll
        for (int r = 0; r < 4; ++r) {
          const int rowL = fm * 16 + quad * 4 + r;
          SM[colL * 72 + rowL] = (bf16)(acc[fm][fn][r] + bvv);
        }
      }
    __syncthreads();
#pragma unroll
    for (int i = 0; i < 4; ++i) {
      const int c = i * 256 + threadIdx.x;     // 1024 chunks
      const int colL = c >> 3, rw = (c & 7) * 8;
      *(bf16x8*)&vt[(size_t)(ncol0 + colL) * 4096 + m0 + rw] =
          *(const bf16x8*)&SM[colL * 72 + rw];
    }
  }
}

// Split-K GEMM (MT=64) -> f32 partials Cp[z][4096][N].
__global__ __launch_bounds__(256, 4) void k_gemm_sk(
    const bf16* __restrict__ A, const bf16* __restrict__ B,
    float* __restrict__ Cp, int N, int K, int Ksplit)
{
  __shared__ __align__(16) bf16 As[64 * 64];
  __shared__ __align__(16) bf16 Bs[128 * 64];
  const int m0 = blockIdx.x * 64, n0 = blockIdx.y * 128;
  const int kbeg = blockIdx.z * Ksplit;
  f32x4 acc[4][2] = {};
  gemm_core_async<64>(A, B, As, Bs, acc, K, m0, n0, kbeg, kbeg + Ksplit);

  const int lane15 = threadIdx.x & 15;
  const int quad   = (threadIdx.x & 63) >> 4;
  const int wave   = threadIdx.x >> 6;
  const int wn     = wave << 5;
  float* Cz = Cp + (size_t)blockIdx.z * 4096 * N;
#pragma unroll
  for (int fm = 0; fm < 4; ++fm)
#pragma unroll
    for (int fn = 0; fn < 2; ++fn) {
      const int col = n0 + wn + fn * 16 + lane15;
#pragma unroll
      for (int r = 0; r < 4; ++r) {
        const int row = m0 + fm * 16 + quad * 4 + r;
        Cz[(size_t)row * N + col] = acc[fm][fn][r];
      }
    }
}

// Wo projection split-K x2 with fused attention combine: A-tile is built
// on the fly as (sum_s Opart_s) * (1/sum_s l_s), reg-staged into LDS (same
// chunk geometry + swizzle as the async path). The 1/l table is computed
// in-kernel (2-KB LDS, 2 entries/thread).
__global__ __launch_bounds__(256, 4) void k_gemm_sk_ctx(
    const bf16* __restrict__ Op, const float* __restrict__ Lp,
    const bf16* __restrict__ B, float* __restrict__ Cp)
{
  __shared__ __align__(16) bf16 As[64 * 64];
  __shared__ __align__(16) bf16 Bs[128 * 64];
  __shared__ float Rls[64 * 8];
  const int tid    = threadIdx.x;
  const int lane   = tid & 63;
  const int wave   = tid >> 6;
  const int lane15 = lane & 15;
  const int quad   = lane >> 4;
  const int m0 = blockIdx.x * 64, n0 = blockIdx.y * 128;
  const int kbeg = blockIdx.z * 256;

  // prologue: per-row/head reciprocal denominators (512 entries, 2/thread)
#pragma unroll
  for (int e = tid * 2; e < tid * 2 + 2; ++e) {
    const int ri = (m0 + (e >> 3)) * 8 + (e & 7);
    const float l = Lp[ri] + Lp[32768 + ri] + Lp[65536 + ri] + Lp[98304 + ri];
    Rls[e] = 1.0f / l;
  }
  __syncthreads();

  int srA[2], soA[2], srB[4], soB[4];
#pragma unroll
  for (int i = 0; i < 2; ++i) {
    int c  = ((wave * 2 + i) << 6) + lane;
    srA[i] = c >> 3;
    soA[i] = ((c & 7) ^ swz(srA[i])) * 8;
  }
#pragma unroll
  for (int i = 0; i < 4; ++i) {
    int c  = ((wave * 4 + i) << 6) + lane;
    srB[i] = c >> 3;
    soB[i] = ((c & 7) ^ swz(srB[i])) * 8;
  }
  const bf16* Bb = B + (size_t)n0 * 512;

  f32x4 acc[4][2] = {};

  for (int k0 = kbeg; k0 < kbeg + 256; k0 += 64) {
#pragma unroll
    for (int i = 0; i < 4; ++i)
      ASYNC_CP16(Bb + (size_t)srB[i] * 512 + k0 + soB[i], &Bs[(wave * 4 + i) * 512]);
    // reg-staged A: combine 4 partials, scale by 1/l, write LDS (linear dest)
#pragma unroll
    for (int i = 0; i < 2; ++i) {
      const int row = m0 + srA[i];
      const int col = k0 + soA[i];
      const float rl = Rls[srA[i] * 8 + (k0 >> 6)];   // col's head = k0>>6
      const size_t base = (size_t)row * 512 + col;
      bf16x8 o0 = *(const bf16x8*)&Op[base];
      bf16x8 o1 = *(const bf16x8*)&Op[(size_t)1 * 4096 * 512 + base];
      bf16x8 o2 = *(const bf16x8*)&Op[(size_t)2 * 4096 * 512 + base];
      bf16x8 o3 = *(const bf16x8*)&Op[(size_t)3 * 4096 * 512 + base];
      bf16x8 y;
#pragma unroll
      for (int j = 0; j < 8; ++j)
        y[j] = (bf16)(((float)o0[j] + (float)o1[j] + (float)o2[j] + (float)o3[j]) * rl);
      *(bf16x8*)&As[(wave * 2 + i) * 512 + lane * 8] = y;
    }
    __syncthreads();

#pragma unroll
    for (int kk = 0; kk < 2; ++kk) {
      bf16x8 af[4], bfr[2];
#pragma unroll
      for (int f = 0; f < 4; ++f) {
        const int ra = f * 16 + lane15;
        af[f] = *(const bf16x8*)&As[ra * 64 + (((kk * 4 + quad) ^ swz(ra)) * 8)];
      }
#pragma unroll
      for (int f = 0; f < 2; ++f) {
        const int rb = (wave << 5) + f * 16 + lane15;
        bfr[f] = *(const bf16x8*)&Bs[rb * 64 + (((kk * 4 + quad) ^ swz(rb)) * 8)];
      }
#pragma unroll
      for (int fm = 0; fm < 4; ++fm)
#pragma unroll
        for (int fn = 0; fn < 2; ++fn)
          acc[fm][fn] = __builtin_amdgcn_mfma_f32_16x16x32_bf16(
              af[fm], bfr[fn], acc[fm][fn], 0, 0, 0);
    }
    __syncthreads();
  }

  float* Cz = Cp + (size_t)blockIdx.z * 4096 * 512;
  const int wn = wave << 5;
#pragma unroll
  for (int fm = 0; fm < 4; ++fm)
#pragma unroll
    for (int fn = 0; fn < 2; ++fn) {
      const int col = n0 + wn + fn * 16 + lane15;
#pragma unroll
      for (int r = 0; r < 4; ++r) {
        const int row = m0 + fm * 16 + quad * 4 + r;
        Cz[(size_t)row * 512 + col] = acc[fm][fn][r];
      }
    }
}

// ---------------------------------------------------------------------------
// Flash attention, split-K x4, 32 q-rows/wave (R0 structure; verified local
// optimum). R7: QK^T computed with SWAPPED operands mfma(K,Q) -> output
// D[key][q]: col=lane15=q-row, row=quad*4+r=key. P-values per lane are 4
// consecutive keys -> one bf16x4 ds_write_b64 per (g,mt) (32 b16-writes ->
// 8 b64-writes, perfect 4/bank distribution) and mask loads drop 8 -> 2 per
// wave-tile (q-row lane-fixed). PV phase / la / epilogue unchanged.
// ---------------------------------------------------------------------------
__global__ __launch_bounds__(256, 4) void k_attn(
    const bf16* __restrict__ Q, const bf16* __restrict__ Km,
    const bf16* __restrict__ Vt, const unsigned long long* __restrict__ mb,
    bf16* __restrict__ Opart, float* __restrict__ Lpart)
{
  __shared__ __align__(16) bf16 Ks[64 * 64];
  __shared__ __align__(16) bf16 Vs[64 * 64];
  __shared__ __align__(16) bf16 Plb[4][32 * 72];

  const int tid    = threadIdx.x;
  const int wave   = tid >> 6;
  const int lane   = tid & 63;
  const int lane15 = lane & 15;
  const int quad   = lane >> 4;
  const int sp     = blockIdx.x & 3;
  const int hd     = (blockIdx.x >> 2) & 7;
  const int qt     = blockIdx.x >> 5;
  const int qrow   = qt * 128 + wave * 32;

  bf16x8 qf[2][2];
#pragma unroll
  for (int mt = 0; mt < 2; ++mt)
#pragma unroll
    for (int c = 0; c < 2; ++c)
      qf[mt][c] = *(const bf16x8*)&Q[(size_t)(qrow + mt * 16 + lane15) * 512 +
                                     hd * 64 + c * 32 + quad * 8];

  // async staging bases (chunk geometry identical to GEMM core, 2 instrs/wave)
  int srK[2], soK[2];
#pragma unroll
  for (int i = 0; i < 2; ++i) {
    int c  = ((wave * 2 + i) << 6) + lane;
    srK[i] = c >> 3;
    soK[i] = ((c & 7) ^ swz(srK[i])) * 8;
  }
  const bf16* KmB[2] = {
      Km + (size_t)srK[0] * 512 + hd * 64 + soK[0],
      Km + (size_t)srK[1] * 512 + hd * 64 + soK[1]};
  const bf16* VtB[2] = {
      Vt + (size_t)(hd * 64 + srK[0]) * 4096 + soK[0],
      Vt + (size_t)(hd * 64 + srK[1]) * 4096 + soK[1]};

  bf16x8 ones;
#pragma unroll
  for (int j = 0; j < 8; ++j) ones[j] = (bf16)1.0f;

  f32x4 o[2][4] = {};
  f32x4 la[2]   = {};

  for (int kt = sp * 16; kt < sp * 16 + 16; ++kt) {
    const int kb = kt * 64;
#pragma unroll
    for (int i = 0; i < 2; ++i) {
      ASYNC_CP16(KmB[i] + (size_t)kb * 512, &Ks[(wave * 2 + i) * 512]);
      ASYNC_CP16(VtB[i] + kb,               &Vs[(wave * 2 + i) * 512]);
    }
    __syncthreads();

    // q-row is lane-fixed in swapped layout: one mask word per mt covers
    // the lane's entire key-tile
    unsigned long long mwq[2];
#pragma unroll
    for (int mt = 0; mt < 2; ++mt)
      mwq[mt] = mb[(size_t)(qrow + mt * 16 + lane15) * 64 + kt];

#pragma unroll
    for (int g = 0; g < 4; ++g) {
      const int row = g * 16 + lane15;
      bf16x8 k0f = *(const bf16x8*)&Ks[row * 64 + ((quad       ^ swz(row)) * 8)];
      bf16x8 k1f = *(const bf16x8*)&Ks[row * 64 + (((4 + quad) ^ swz(row)) * 8)];
#pragma unroll
      for (int mt = 0; mt < 2; ++mt) {
        f32x4 s = {};
        s = __builtin_amdgcn_mfma_f32_16x16x32_bf16(k0f, qf[mt][0], s, 0, 0, 0);
        s = __builtin_amdgcn_mfma_f32_16x16x32_bf16(k1f, qf[mt][1], s, 0, 0, 0);
        const unsigned nib = (unsigned)(mwq[mt] >> (g * 16 + quad * 4)) & 0xFu;
        bf16x4 pv;
#pragma unroll
        for (int r = 0; r < 4; ++r)
          pv[r] = (nib & (1u << r)) ? (bf16)__builtin_amdgcn_exp2f(s[r])
                                    : (bf16)0.0f;
        *(bf16x4*)&Plb[wave][(mt * 16 + lane15) * 72 + g * 16 + quad * 4] = pv;
      }
    }

#pragma unroll
    for (int c2 = 0; c2 < 2; ++c2) {
      bf16x8 vf[4];
#pragma unroll
      for (int g2 = 0; g2 < 4; ++g2) {
        const int row = g2 * 16 + lane15;
        vf[g2] = *(const bf16x8*)&Vs[row * 64 + (((c2 * 4 + quad) ^ swz(row)) * 8)];
      }
#pragma unroll
      for (int mt = 0; mt < 2; ++mt) {
        bf16x8 pa = *(const bf16x8*)&Plb[wave][(mt * 16 + lane15) * 72 + c2 * 32 + quad * 8];
        la[mt] = __builtin_amdgcn_mfma_f32_16x16x32_bf16(pa, ones, la[mt], 0, 0, 0);
#pragma unroll
        for (int g2 = 0; g2 < 4; ++g2)
          o[mt][g2] = __builtin_amdgcn_mfma_f32_16x16x32_bf16(pa, vf[g2], o[mt][g2], 0, 0, 0);
      }
    }
    __syncthreads();
  }

  bf16* Oz = Opart + (size_t)sp * 4096 * 512;
#pragma unroll
  for (int mt = 0; mt < 2; ++mt) {
#pragma unroll
    for (int g2 = 0; g2 < 4; ++g2)
#pragma unroll
      for (int r = 0; r < 4; ++r) {
        const int row = qrow + mt * 16 + quad * 4 + r;
        Oz[(size_t)row * 512 + hd * 64 + g2 * 16 + lane15] = (bf16)o[mt][g2][r];
      }
    if (lane15 == 0) {
#pragma unroll
      for (int r = 0; r < 4; ++r)
        Lpart[sp * 32768 + (qrow + mt * 16 + quad * 4 + r) * 8 + hd] = la[mt][r];
    }
  }
}

// ---------------------------------------------------------------------------
// Fused: split-K combine + bias + residual + LayerNorm. N=512 fixed.
// ---------------------------------------------------------------------------
template <int F32OUT>
__global__ __launch_bounds__(256) void k_addln_sk(
    const bf16* __restrict__ x, const float* __restrict__ Cp,
    const float* __restrict__ bias,
    const float* __restrict__ gam, const float* __restrict__ bet,
    void* __restrict__ out)
{
  const int wave = threadIdx.x >> 6, lane = threadIdx.x & 63;
  const int row  = blockIdx.x * 4 + wave;
  const size_t base = (size_t)row * 512 + lane * 8;
  const int col = lane * 8;
  bf16x8 xv = *(const bf16x8*)(x + base);
  const float* p0 = Cp + base;
  const float* p1 = Cp + (size_t)4096 * 512 + base;
  f32x4 a0 = *(const f32x4*)p0, a1 = *(const f32x4*)(p0 + 4);
  f32x4 b0 = *(const f32x4*)p1, b1 = *(const f32x4*)(p1 + 4);
  f32x4 c0 = *(const f32x4*)(bias + col), c1 = *(const f32x4*)(bias + col + 4);
  float v[8], s = 0.0f, s2 = 0.0f;
#pragma unroll
  for (int j = 0; j < 4; ++j) {
    v[j]     = (float)xv[j]     + a0[j] + b0[j] + c0[j];
    v[4 + j] = (float)xv[4 + j] + a1[j] + b1[j] + c1[j];
  }
#pragma unroll
  for (int j = 0; j < 8; ++j) { s += v[j]; s2 += v[j] * v[j]; }
#pragma unroll
  for (int d = 1; d < 64; d <<= 1) { s += __shfl_xor(s, d, 64); s2 += __shfl_xor(s2, d, 64); }
  const float mu  = s * (1.0f / 512.0f);
  const float var = s2 * (1.0f / 512.0f) - mu * mu;
  const float rs  = rsqrtf(var + 1e-5f);
  f32x4 g0 = *(const f32x4*)(gam + col), g1 = *(const f32x4*)(gam + col + 4);
  f32x4 e0 = *(const f32x4*)(bet + col), e1 = *(const f32x4*)(bet + col + 4);
  if (F32OUT) {
    float* o = (float*)out + base;
#pragma unroll
    for (int j = 0; j < 4; ++j) {
      o[j]     = ((v[j] - mu) * rs) * g0[j] + e0[j];
      o[4 + j] = ((v[4 + j] - mu) * rs) * g1[j] + e1[j];
    }
  } else {
    bf16x8 ov;
#pragma unroll
    for (int j = 0; j < 4; ++j) {
      ov[j]     = (bf16)(((v[j] - mu) * rs) * g0[j] + e0[j]);
      ov[4 + j] = (bf16)(((v[4 + j] - mu) * rs) * g1[j] + e1[j]);
    }
    *(bf16x8*)((bf16*)out + base) = ov;
  }
}

// ---------------------------------------------------------------------------
extern "C" void kernel_launch(void* const* d_in, const int* in_sizes, int n_in,
                              void* d_out, int out_size, void* d_ws, size_t ws_size,
                              hipStream_t stream)
{
  const int*   adj = (const int*)  d_in[1];
  const float* bq  = (const float*)d_in[3];
  const float* bk  = (const float*)d_in[5];
  const float* bv  = (const float*)d_in[7];
  const float* bo  = (const float*)d_in[9];
  const float* b1  = (const float*)d_in[11];
  const float* b2  = (const float*)d_in[13];
  const float* g1  = (const float*)d_in[14];
  const float* be1 = (const float*)d_in[15];
  const float* g2  = (const float*)d_in[16];
  const float* be2 = (const float*)d_in[17];

  char* ws = (char*)d_ws;
  const size_t MB = 1024 * 1024;

  // bf16 arena. Wq/Wk/Wv are contiguous, forming the concat [1536,512] matrix.
  bf16* hb  = (bf16*)(ws + 0 * MB);                  // 4 MB
  bf16* Wqb = (bf16*)(ws + 4 * MB);                  // concat base
  bf16* Wkb = (bf16*)(ws + 4 * MB + 512 * 1024);
  bf16* Wvb = (bf16*)(ws + 5 * MB);
  bf16* Wob = (bf16*)(ws + 5 * MB + 512 * 1024);
  bf16* W1b = (bf16*)(ws + 6 * MB);                  // 2 MB
  bf16* W2b = (bf16*)(ws + 8 * MB);                  // 2 MB

  // intermediates (lifetime-packed; see per-stage notes)
  bf16* q    = (bf16*)(ws + 12 * MB);   // dead after attn
  bf16* k    = (bf16*)(ws + 16 * MB);   // dead after attn
  bf16* vt   = (bf16*)(ws + 24 * MB);   // dead after attn
  unsigned long long* mbits = (unsigned long long*)(ws + 28 * MB); // 2 MB
  bf16*  Opart = (bf16*)(ws + 34 * MB); // 16 MB, dead after Wo sk-gemm
  float* Lpart = (float*)(ws + 50 * MB);            // 0.5 MB
  float* skP   = (float*)(ws + 12 * MB);// 16 MB f32 partials over q,k,vt (dead)
  bf16* h1   = (bf16*)(ws + 30 * MB);   // 4 MB (free region)
  bf16* ff1  = (bf16*)(ws + 34 * MB);   // 16 MB over Opart (dead post Wo-gemm)

  // cast args
  CastArgs ca;
  const int srcIdx[7] = {0, 2, 4, 6, 8, 10, 12};
  bf16* dsts[7] = {hb, Wqb, Wkb, Wvb, Wob, W1b, W2b};
  int cum = 0;
  for (int t = 0; t < 7; ++t) {
    ca.src[t] = (const float*)d_in[srcIdx[t]];
    ca.dst[t] = dsts[t];
    ca.cum[t] = cum;
    cum += in_sizes[srcIdx[t]] / 8;
  }
  ca.cum[7] = cum;

  const dim3 blk(256);

  // 1. prep: packmask (16384 blocks, 4 words/wave) + cast
  k_prep<<<dim3(16384 + (cum + 255) / 256), blk, 0, stream>>>(adj, mbits, ca, cum);
  // 2. fused QKV (768 blocks); V blocks write vt directly; Q pre-scaled
  k_gemm_qkv<<<dim3(64, 12), blk, 0, stream>>>(hb, Wqb, bq, bk, bv, q, k, vt);
  // 3. flash attention, split-K x4 (1024 blocks)
  k_attn<<<dim3(1024), blk, 0, stream>>>(q, k, vt, mbits, Opart, Lpart);
  // 4. Wo projection with fused O-combine + in-kernel 1/l
  k_gemm_sk_ctx<<<dim3(64, 4, 2), blk, 0, stream>>>(Opart, Lpart, Wob, skP);
  k_addln_sk<0><<<dim3(1024), blk, 0, stream>>>(hb, skP, bo, g1, be1, (void*)h1);
  // 5. ff1 = relu(h1 @ W1^T + b1)  (512 blocks)
  k_gemm<<<dim3(32, 16), blk, 0, stream>>>(h1, W1b, b1, ff1, 2048, 512, 1);
  // 6. ff2 split-K x2 (512 blocks) -> fused combine+LN2 -> d_out (fp32)
  k_gemm_sk<<<dim3(64, 4, 2), blk, 0, stream>>>(ff1, W2b, skP, 512, 2048, 1024);
  k_addln_sk<1><<<dim3(1024), blk, 0, stream>>>(h1, skP, b2, g2, be2, d_out);
}